// Round 3
// baseline (302.293 us; speedup 1.0000x reference)
//
#include <hip/hip_runtime.h>

// RGCN: bucketed atomic-free counting sort + degree-binned dim-sliced bf16 gather
// + pipelined bf16 MFMA GEMM.
// Round-13:
//   - degree-binned permutation of segments (32 buckets) -> wave-max padding
//     inflation 2.65x -> ~1.1x in the gather
//   - v_pk_add_f32 packed accumulate (16 -> 12 VALU per 16B)
//   - scan3s dropped (fix-up folded into scatterA/segOff); permBuild added
//
//   seg(e) = rel(e)*nN + src(e)          (numSeg = nRel*nN)
//   agg[seg,:] = bf16( mean_{e in seg} x[dst_e,:] )
//   out = sum_r agg_r @ W_r^T + x @ root^T + bias   (MFMA 16x16x32 bf16)

#define D 128
#define SCAN_CHUNK 2048
#define SEG_BITS 9
#define SEGS_PER_BUCKET 512
#define NBLK 128            // blocks for histA/scatterA
#define NDEG 32             // degree buckets

typedef __attribute__((ext_vector_type(8))) short short8;
typedef __attribute__((ext_vector_type(4))) float v4f;
typedef __attribute__((ext_vector_type(2))) float f32x2;
typedef __attribute__((ext_vector_type(4))) unsigned uint4v;

#define GLOAD_LDS16(gptr, lptr) \
    __builtin_amdgcn_global_load_lds((const __attribute__((address_space(1))) void*)(gptr), \
                                     (__attribute__((address_space(3))) void*)(lptr), 16, 0, 0)

__device__ __forceinline__ unsigned short f2b(float f) {
    union { float f; unsigned u; } v; v.f = f;
    unsigned r = v.u + 0x7fffu + ((v.u >> 16) & 1u);   // RNE
    return (unsigned short)(r >> 16);
}
__device__ __forceinline__ float blo(unsigned u) {
    union { unsigned u; float f; } v; v.u = u << 16; return v.f;
}
__device__ __forceinline__ float bhi(unsigned u) {
    union { unsigned u; float f; } v; v.u = u & 0xffff0000u; return v.f;
}

// ---------- fp32 -> bf16 bulk convert ----------
// x is written twice: slab-major xB[slice][node][32] (gather, L2-resident slices)
// and row-major xRow[node][128] (9th A slab for the GEMM).
__global__ void cvt_bf16_all(const float* __restrict__ x, long long nx,
                             const float* __restrict__ w, long long nw,
                             const float* __restrict__ root, long long nr,
                             unsigned short* __restrict__ xB,
                             unsigned short* __restrict__ xRow,
                             unsigned short* __restrict__ wB, int nN) {
    long long i = ((long long)blockIdx.x * blockDim.x + threadIdx.x) * 4;
    if (i < nx) {
        float4 v = *(const float4*)(x + i);
        uint2 p;
        p.x = (unsigned)f2b(v.x) | ((unsigned)f2b(v.y) << 16);
        p.y = (unsigned)f2b(v.z) | ((unsigned)f2b(v.w) << 16);
        long long n = i >> 7;
        int d = (int)(i & 127);
        size_t o = (size_t)(d >> 5) * (size_t)nN * 32 + (size_t)n * 32 + (d & 31);
        *(uint2*)(xB + o) = p;
        *(uint2*)(xRow + i) = p;
        return;
    }
    const float* src;
    unsigned short* dst;
    long long j;
    if (i < nx + nw) { src = w; dst = wB; j = i - nx; }
    else if (i < nx + nw + nr) { src = root; dst = wB + nw; j = i - nx - nw; }
    else return;
    float4 v = *(const float4*)(src + j);
    uint2 p;
    p.x = (unsigned)f2b(v.x) | ((unsigned)f2b(v.y) << 16);
    p.y = (unsigned)f2b(v.z) | ((unsigned)f2b(v.w) << 16);
    *(uint2*)(dst + j) = p;
}

// ---------- phase A: per-block bucket histogram (LDS atomics only) ----------
__global__ __launch_bounds__(256)
void histA(const int* __restrict__ ei, const int* __restrict__ et,
           int* __restrict__ blockHist, int nE, int nN, int B, int epb) {
    __shared__ int lh[1024];
    const int tid = threadIdx.x;
    for (int b = tid; b < B; b += 256) lh[b] = 0;
    __syncthreads();
    const int base = blockIdx.x * epb;
    const int lim = min(base + epb, nE);
    for (int e = base + tid; e < lim; e += 256) {
        int seg = et[e] * nN + ei[e];
        atomicAdd(&lh[seg >> SEG_BITS], 1);
    }
    __syncthreads();
    for (int b = tid; b < B; b += 256)
        blockHist[b * NBLK + blockIdx.x] = lh[b];
}

// ---------- scan of blockHist (bucket-major) ----------
// scan1 also re-zeroes the degree histogram + cursors each iteration.
__global__ __launch_bounds__(256)
void scan1(const int* __restrict__ in, int* __restrict__ excl,
           int* __restrict__ blockSums, int* __restrict__ degHist,
           int* __restrict__ cursor32, int n) {
    if (blockIdx.x == 0 && threadIdx.x < 2 * NDEG) {
        if (threadIdx.x < NDEG) degHist[threadIdx.x] = 0;
        else cursor32[threadIdx.x - NDEG] = 0;
    }
    __shared__ int t[256];
    const int tid = threadIdx.x;
    const int base = blockIdx.x * SCAN_CHUNK + tid * 8;
    int v[8];
    int tot = 0;
#pragma unroll
    for (int i = 0; i < 8; i++) {
        v[i] = (base + i < n) ? in[base + i] : 0;
        tot += v[i];
    }
    t[tid] = tot;
    __syncthreads();
    for (int off = 1; off < 256; off <<= 1) {
        int add = (tid >= off) ? t[tid - off] : 0;
        __syncthreads();
        t[tid] += add;
        __syncthreads();
    }
    int run = t[tid] - tot;
#pragma unroll
    for (int i = 0; i < 8; i++) {
        if (base + i < n) excl[base + i] = run;
        run += v[i];
    }
    if (tid == 255) blockSums[blockIdx.x] = t[255];
}

__global__ __launch_bounds__(256)
void scan2(int* __restrict__ blockSums, int nb) {
    __shared__ int t[256];
    const int tid = threadIdx.x;
    int v = (tid < nb) ? blockSums[tid] : 0;
    t[tid] = v;
    __syncthreads();
    for (int off = 1; off < 256; off <<= 1) {
        int add = (tid >= off) ? t[tid - off] : 0;
        __syncthreads();
        t[tid] += add;
        __syncthreads();
    }
    if (tid < nb) blockSums[tid] = t[tid] - v;
}

// ---------- phase C: bucket scatter (adds blockSums fix-up inline) ----------
__global__ __launch_bounds__(256)
void scatterA(const int* __restrict__ ei, const int* __restrict__ et,
              const int* __restrict__ scanned, const int* __restrict__ blockSums,
              unsigned* __restrict__ bucketEdges,
              int nE, int nN, int B, int epb) {
    __shared__ int cur[1024];
    const int tid = threadIdx.x;
    for (int b = tid; b < B; b += 256) {
        int idx = b * NBLK + blockIdx.x;
        cur[b] = scanned[idx] + blockSums[idx >> 11];   // SCAN_CHUNK = 2048
    }
    __syncthreads();
    const int base = blockIdx.x * epb;
    const int lim = min(base + epb, nE);
    for (int e = base + tid; e < lim; e += 256) {
        int seg = et[e] * nN + ei[e];
        int bkt = seg >> SEG_BITS;
        unsigned pk = ((unsigned)(seg & (SEGS_PER_BUCKET - 1)) << 16) | (unsigned)ei[nE + e];
        int pos = atomicAdd(&cur[bkt], 1);
        bucketEdges[pos] = pk;
    }
}

// ---------- phase D: per-bucket seg offsets + sorted ushort dst + deg hist ----------
__global__ __launch_bounds__(256)
void segOff(const unsigned* __restrict__ bucketEdges, const int* __restrict__ scanned,
            const int* __restrict__ blockSums,
            int* __restrict__ off, unsigned short* __restrict__ sortedDst,
            int* __restrict__ degHist, int nE, int numSeg, int B) {
    __shared__ int lh[SEGS_PER_BUCKET];
    __shared__ int sc[256];
    __shared__ int lcur[SEGS_PER_BUCKET];
    __shared__ int dh[NDEG];
    const int tid = threadIdx.x;
    const int b = blockIdx.x;
    const int i0 = b * NBLK;
    const int eBase = scanned[i0] + blockSums[i0 >> 11];
    int eEnd = nE;
    if (b + 1 < B) {
        const int i1 = (b + 1) * NBLK;
        eEnd = scanned[i1] + blockSums[i1 >> 11];
    }
    const int segBase = b * SEGS_PER_BUCKET;
    const int segLim = min(SEGS_PER_BUCKET, numSeg - segBase);

    lh[2 * tid] = 0; lh[2 * tid + 1] = 0;
    if (tid < NDEG) dh[tid] = 0;
    __syncthreads();
    for (int i = eBase + tid; i < eEnd; i += 256)
        atomicAdd(&lh[bucketEdges[i] >> 16], 1);
    __syncthreads();
    int a0 = lh[2 * tid], a1 = lh[2 * tid + 1];
    if (2 * tid < segLim)     atomicAdd(&dh[min(a0, NDEG - 1)], 1);
    if (2 * tid + 1 < segLim) atomicAdd(&dh[min(a1, NDEG - 1)], 1);
    sc[tid] = a0 + a1;
    __syncthreads();
    for (int o = 1; o < 256; o <<= 1) {
        int add = (tid >= o) ? sc[tid - o] : 0;
        __syncthreads();
        sc[tid] += add;
        __syncthreads();
    }
    int pairBase = sc[tid] - (a0 + a1);
    int g0 = eBase + pairBase;
    int g1 = g0 + a0;
    lcur[2 * tid] = g0;
    lcur[2 * tid + 1] = g1;
    if (2 * tid < segLim)     off[segBase + 2 * tid] = g0;
    if (2 * tid + 1 < segLim) off[segBase + 2 * tid + 1] = g1;
    if (b == B - 1 && tid == 0) off[numSeg] = nE;
    __syncthreads();
    for (int i = eBase + tid; i < eEnd; i += 256) {
        unsigned u = bucketEdges[i];
        int pos = atomicAdd(&lcur[u >> 16], 1);
        sortedDst[pos] = (unsigned short)(u & 0xFFFFu);
    }
    __syncthreads();
    if (tid < NDEG && dh[tid]) atomicAdd(&degHist[tid], dh[tid]);
}

// ---------- degree-binned permutation build ----------
// perm = segment ids grouped by degree bucket (order within bucket arbitrary).
__global__ __launch_bounds__(256)
void permBuild(const int* __restrict__ off, const int* __restrict__ degHist,
               int* __restrict__ cursor32, int* __restrict__ perm, int numSeg) {
    __shared__ int lcnt[NDEG];
    __shared__ int lbase[NDEG];
    __shared__ int gbase[NDEG];
    const int tid = threadIdx.x;
    if (tid < NDEG) lcnt[tid] = 0;
    __syncthreads();
    int s[4], bkt[4], lpos[4];
#pragma unroll
    for (int i = 0; i < 4; i++) {
        s[i] = blockIdx.x * 1024 + i * 256 + tid;
        bkt[i] = -1;
        if (s[i] < numSeg) {
            int c = off[s[i] + 1] - off[s[i]];
            bkt[i] = min(c, NDEG - 1);
            lpos[i] = atomicAdd(&lcnt[bkt[i]], 1);
        }
    }
    __syncthreads();
    if (tid < NDEG) {
        lbase[tid] = lcnt[tid] ? atomicAdd(&cursor32[tid], lcnt[tid]) : 0;
        int run = 0;
        for (int k = 0; k < tid; k++) run += degHist[k];
        gbase[tid] = run;
    }
    __syncthreads();
#pragma unroll
    for (int i = 0; i < 4; i++)
        if (bkt[i] >= 0)
            perm[gbase[bkt[i]] + lbase[bkt[i]] + lpos[i]] = s[i];
}

// ---------- gather: degree-binned, dim-sliced, 4 lanes/edge, 16 segs/wave ----------
// blockIdx.y = slice (32 dims); per-slice xB slab = 3.2 MB -> per-XCD-L2 resident.
// Segments taken in perm order -> same-degree waves -> minimal padding.
__global__ __launch_bounds__(256)
void rgcn_gather(const unsigned short* __restrict__ xB,
                 const unsigned short* __restrict__ sortedDst,
                 const int* __restrict__ off, const int* __restrict__ perm,
                 unsigned short* __restrict__ Abuf, int nN, int numSeg,
                 size_t SL, unsigned long long M) {
    const int tid = threadIdx.x;
    const int lane = tid & 63;
    const int idx4 = lane & 3;       // lane within 4-lane group (8 dims each)
    const int grp = lane >> 2;       // 16 groups per wave
    const int wv = tid >> 6;
    const int gsi = blockIdx.x * 64 + wv * 16 + grp;
    const int sl = blockIdx.y;       // dims [sl*32, sl*32+32)
    const bool valid = (gsi < numSeg);
    const int seg = valid ? perm[gsi] : 0;

    const int start = off[seg];
    int cnt = valid ? (off[seg + 1] - start) : 0;

    int mx = cnt;
    mx = max(mx, __shfl_xor(mx, 4));
    mx = max(mx, __shfl_xor(mx, 8));
    mx = max(mx, __shfl_xor(mx, 16));
    mx = max(mx, __shfl_xor(mx, 32));

    f32x2 acc2[4];
#pragma unroll
    for (int i = 0; i < 4; i++) acc2[i] = (f32x2){0.f, 0.f};

    // slab-major: xB[sl][node][32]; each lane owns 8 consecutive dims
    const unsigned short* xSlab = xB + (size_t)sl * nN * 32 + idx4 * 8;

    for (int b = 0; b < mx; b += 4) {
        int myDst = (b + idx4 < cnt) ? (int)sortedDst[start + b + idx4] : 0;
        uint4v v[4];
#pragma unroll
        for (int j = 0; j < 4; j++) {
            // batch 4 independent predicated loads (act uniform per group)
            int dst = __shfl(myDst, grp * 4 + j);
            bool act = (b + j < cnt);
            v[j] = act ? *(const uint4v*)(xSlab + ((size_t)dst << 5))
                       : (uint4v){0u, 0u, 0u, 0u};
        }
#pragma unroll
        for (int j = 0; j < 4; j++) {
            f32x2 t0 = (f32x2){blo(v[j].x), bhi(v[j].x)};
            f32x2 t1 = (f32x2){blo(v[j].y), bhi(v[j].y)};
            f32x2 t2 = (f32x2){blo(v[j].z), bhi(v[j].z)};
            f32x2 t3 = (f32x2){blo(v[j].w), bhi(v[j].w)};
            asm("v_pk_add_f32 %0, %0, %1" : "+v"(acc2[0]) : "v"(t0));
            asm("v_pk_add_f32 %0, %0, %1" : "+v"(acc2[1]) : "v"(t1));
            asm("v_pk_add_f32 %0, %0, %1" : "+v"(acc2[2]) : "v"(t2));
            asm("v_pk_add_f32 %0, %0, %1" : "+v"(acc2[3]) : "v"(t3));
        }
    }

    if (valid) {
        const int r = (int)(((unsigned long long)seg * M) >> 48);  // seg / nN
        const int n = seg - r * nN;
        float s = cnt > 0 ? 1.0f / (float)cnt : 0.f;
        uint4v pkt;
        pkt.x = (unsigned)f2b(acc2[0].x * s) | ((unsigned)f2b(acc2[0].y * s) << 16);
        pkt.y = (unsigned)f2b(acc2[1].x * s) | ((unsigned)f2b(acc2[1].y * s) << 16);
        pkt.z = (unsigned)f2b(acc2[2].x * s) | ((unsigned)f2b(acc2[2].y * s) << 16);
        pkt.w = (unsigned)f2b(acc2[3].x * s) | ((unsigned)f2b(acc2[3].y * s) << 16);
        // nt store (64B sectors, no amplification — WRITE_SIZE was exact in R2)
        __builtin_nontemporal_store(pkt,
            (uint4v*)(Abuf + (size_t)r * SL + (size_t)n * D + sl * 32 + idx4 * 8));
    }
}

// ---------- MFMA GEMM: M=nN, N=128, K=(nRel+1)*128 ----------
// A = [nRel+1][nNalloc][128] contiguous (8 agg slabs + xRow); B = wB [nRel+1][128][128].
// Pipelined 2-phase: global_load_lds(16B) into linear LDS, st_8x16 XOR swizzle
// applied on the global SOURCE address; ds_read applies the same XOR. 1 barrier/step.
__global__ __launch_bounds__(256)
void rgcn_gemm_mfma(const unsigned short* __restrict__ A,
                    const unsigned short* __restrict__ wB,
                    const float* __restrict__ bias,
                    float* __restrict__ out, int nN, int nRel, size_t SL) {
    __shared__ __align__(16) unsigned short As[2][64 * 64];    // [buf][row][64k]
    __shared__ __align__(16) unsigned short Bs[2][128 * 64];   // [buf][ocol][64k]
    const int tid = threadIdx.x;
    const int wave = tid >> 6;
    const int lane = tid & 63;
    const int wm = wave & 1;
    const int wn = wave >> 1;
    const int m16 = lane & 15;
    const int q = lane >> 4;
    const int row0 = blockIdx.x * 64;

    v4f acc[2][4];
#pragma unroll
    for (int i = 0; i < 2; i++)
#pragma unroll
        for (int j = 0; j < 4; j++) acc[i][j] = (v4f){0.f, 0.f, 0.f, 0.f};

    // ds_read offsets (ushort idx), swizzle: granule g read at slot g ^ (row&7);
    // row&7 == m16&7 for all frags (row/ocol = mult-of-8 + m16).
    const int sw = m16 & 7;
    int aoff[2][2], boff[4][2];
#pragma unroll
    for (int mt = 0; mt < 2; mt++) {
        int row = wm * 32 + mt * 16 + m16;
#pragma unroll
        for (int kb = 0; kb < 2; kb++)
            aoff[mt][kb] = row * 64 + (((kb * 4 + q) ^ sw) * 8);
    }
#pragma unroll
    for (int nt = 0; nt < 4; nt++) {
        int o = wn * 64 + nt * 16 + m16;
#pragma unroll
        for (int kb = 0; kb < 2; kb++)
            boff[nt][kb] = o * 64 + (((kb * 4 + q) ^ sw) * 8);
    }

    // staging: lane l of issue i writes LDS slot (base_i + l); slot -> row=slot>>3,
    // gs=slot&7; source granule gd = gs ^ (row&7) = (l&7) ^ (l>>3) (i adds 8 rows).
    const int l8 = lane >> 3;
    const int gd = (lane & 7) ^ l8;
    const size_t aBase = (size_t)(row0 + wave * 16 + l8) * D + gd * 8;  // elements
    const size_t bBase = (size_t)(wave * 32 + l8) * D + gd * 8;

    const int nT = 2 * (nRel + 1);    // 18 K-steps of 64

#define STAGE(buf, t) do { \
        const int s_ = (t) >> 1, h_ = (t) & 1; \
        const unsigned short* ga_ = A + (size_t)s_ * SL + h_ * 64 + aBase; \
        const unsigned short* gb_ = wB + (size_t)s_ * (D * D) + h_ * 64 + bBase; \
        GLOAD_LDS16(ga_,        &As[buf][(wave * 2 + 0) * 512]); \
        GLOAD_LDS16(ga_ + 1024, &As[buf][(wave * 2 + 1) * 512]); \
        GLOAD_LDS16(gb_,        &Bs[buf][(wave * 4 + 0) * 512]); \
        GLOAD_LDS16(gb_ + 1024, &Bs[buf][(wave * 4 + 1) * 512]); \
        GLOAD_LDS16(gb_ + 2048, &Bs[buf][(wave * 4 + 2) * 512]); \
        GLOAD_LDS16(gb_ + 3072, &Bs[buf][(wave * 4 + 3) * 512]); \
    } while (0)

    STAGE(0, 0);
    __syncthreads();                    // vmcnt(0) drain emitted by compiler
    int cur = 0;
    for (int t = 0; t < nT; ++t) {
        if (t + 1 < nT) STAGE(cur ^ 1, t + 1);   // next tile in flight over compute
        const unsigned short* Ab = As[cur];
        const unsigned short* Bb = Bs[cur];
        short8 a[2][2], b[4][2];
#pragma unroll
        for (int kb = 0; kb < 2; kb++) {
#pragma unroll
            for (int mt = 0; mt < 2; mt++)
                a[mt][kb] = *(const short8*)&Ab[aoff[mt][kb]];
#pragma unroll
            for (int nt = 0; nt < 4; nt++)
                b[nt][kb] = *(const short8*)&Bb[boff[nt][kb]];
        }
#pragma unroll
        for (int kb = 0; kb < 2; kb++)
#pragma unroll
            for (int mt = 0; mt < 2; mt++)
#pragma unroll
                for (int nt = 0; nt < 4; nt++)
                    acc[mt][nt] = __builtin_amdgcn_mfma_f32_16x16x32_bf16(
                        a[mt][kb], b[nt][kb], acc[mt][nt], 0, 0, 0);
        __syncthreads();
        cur ^= 1;
    }
#undef STAGE

#pragma unroll
    for (int mt = 0; mt < 2; mt++) {
#pragma unroll
        for (int nt = 0; nt < 4; nt++) {
            int col = wn * 64 + nt * 16 + m16;
            float bi = bias[col];
#pragma unroll
            for (int reg = 0; reg < 4; reg++) {
                int rrow = row0 + wm * 32 + mt * 16 + q * 4 + reg;
                if (rrow < nN)
                    out[(size_t)rrow * D + col] = acc[mt][nt][reg] + bi;
            }
        }
    }
}

extern "C" void kernel_launch(void* const* d_in, const int* in_sizes, int n_in,
                              void* d_out, int out_size, void* d_ws, size_t ws_size,
                              hipStream_t stream) {
    const float* x    = (const float*)d_in[0];
    const int*   ei   = (const int*)d_in[1];
    const int*   et   = (const int*)d_in[2];
    const float* w    = (const float*)d_in[3];
    const float* root = (const float*)d_in[4];
    const float* bias = (const float*)d_in[5];
    float* out = (float*)d_out;

    const int nN   = in_sizes[0] / D;        // 50000 (< 65536 for ushort dst)
    const int nE   = in_sizes[2];
    const int nRel = in_sizes[3] / (D * D);
    const int numSeg = nRel * nN;
    const int B = (numSeg + SEGS_PER_BUCKET - 1) >> SEG_BITS;   // 782 (<= 1024)
    const int nBH = B * NBLK;
    const int epb = (nE + NBLK - 1) / NBLK;
    const int nNalloc = (nN + 63) & ~63;     // pad rows to 64; garbage rows benign
    const size_t SL = (size_t)nNalloc * D;   // elements per A slab
    const unsigned long long M = ((1ULL << 48) + nN - 1) / nN;  // magic for /nN

    // workspace layout (~157 MB; ws proven >= 218 MB in round 4)
    char* p = (char*)d_ws;
    unsigned* bucketEdges   = (unsigned*)p;        p += (size_t)nE * sizeof(unsigned);
    unsigned short* sortedDst = (unsigned short*)p; p += (size_t)nE * sizeof(unsigned short);
    p = (char*)(((uintptr_t)p + 255) & ~(uintptr_t)255);
    int* off       = (int*)p;  p += (size_t)(numSeg + 1) * sizeof(int);
    int* blockHist = (int*)p;  p += (size_t)nBH * sizeof(int);
    int* scanned   = (int*)p;  p += (size_t)nBH * sizeof(int);
    int* blockSums = (int*)p;  p += 256 * sizeof(int);
    int* degHist   = (int*)p;  p += NDEG * sizeof(int);
    int* cursor32  = (int*)p;  p += NDEG * sizeof(int);
    p = (char*)(((uintptr_t)p + 255) & ~(uintptr_t)255);
    int* perm      = (int*)p;  p += (size_t)numSeg * sizeof(int);
    p = (char*)(((uintptr_t)p + 255) & ~(uintptr_t)255);
    unsigned short* xB   = (unsigned short*)p;  p += (size_t)nN * D * sizeof(unsigned short);
    unsigned short* wBc  = (unsigned short*)p;  p += (size_t)(nRel + 1) * D * D * sizeof(unsigned short);
    p = (char*)(((uintptr_t)p + 255) & ~(uintptr_t)255);
    unsigned short* Abuf = (unsigned short*)p;     // [nRel+1][nNalloc][128]
    unsigned short* xRow = Abuf + (size_t)nRel * SL;

    const int nScanBlocks = (nBH + SCAN_CHUNK - 1) / SCAN_CHUNK;  // 49 <= 256

    histA<<<NBLK, 256, 0, stream>>>(ei, et, blockHist, nE, nN, B, epb);
    scan1<<<nScanBlocks, 256, 0, stream>>>(blockHist, scanned, blockSums, degHist, cursor32, nBH);
    scan2<<<1, 256, 0, stream>>>(blockSums, nScanBlocks);
    scatterA<<<NBLK, 256, 0, stream>>>(ei, et, scanned, blockSums, bucketEdges, nE, nN, B, epb);
    segOff<<<B, 256, 0, stream>>>(bucketEdges, scanned, blockSums, off, sortedDst, degHist,
                                  nE, numSeg, B);
    permBuild<<<(numSeg + 1023) / 1024, 256, 0, stream>>>(off, degHist, cursor32, perm, numSeg);

    long long nx = (long long)nN * D;
    long long nw = (long long)nRel * D * D;
    long long nr = (long long)D * D;
    long long ncvt = (nx + nw + nr) / 4;
    cvt_bf16_all<<<(int)((ncvt + 255) / 256), 256, 0, stream>>>(x, nx, w, nw, root, nr,
                                                                xB, xRow, wBc, nN);

    dim3 gg((numSeg + 63) / 64, 4);
    rgcn_gather<<<gg, 256, 0, stream>>>(xB, sortedDst, off, perm, Abuf, nN, numSeg, SL, M);

    rgcn_gemm_mfma<<<(nN + 63) / 64, 256, 0, stream>>>(Abuf, wBc, bias, out, nN, nRel, SL);
}

// Round 4
// 289.480 us; speedup vs baseline: 1.0443x; 1.0443x over previous
//
#include <hip/hip_runtime.h>

// RGCN: bucketed atomic-free counting sort + windowed degree-binned dim-sliced
// bf16 gather + pipelined bf16 MFMA GEMM.
// Round-14:
//   - degree binning made WINDOW-LOCAL (sorted by degree within each 512-seg
//     bucket, built inside segOff) -> same-degree waves AND L2 locality:
//     R3's global perm thrashed the xB slice out of L2 (FETCH 66->155 MB)
//   - permBuild/degHist/cursor32 deleted; scan1 reverted
//   - keeps: v_pk_add_f32 accumulate, magic-div r recovery, dim-sliced gather,
//     pipelined global_load_lds GEMM
//
//   seg(e) = rel(e)*nN + src(e)          (numSeg = nRel*nN)
//   agg[seg,:] = bf16( mean_{e in seg} x[dst_e,:] )
//   out = sum_r agg_r @ W_r^T + x @ root^T + bias   (MFMA 16x16x32 bf16)

#define D 128
#define SCAN_CHUNK 2048
#define SEG_BITS 9
#define SEGS_PER_BUCKET 512
#define NBLK 128            // blocks for histA/scatterA
#define NDEG 32             // degree buckets

typedef __attribute__((ext_vector_type(8))) short short8;
typedef __attribute__((ext_vector_type(4))) float v4f;
typedef __attribute__((ext_vector_type(2))) float f32x2;
typedef __attribute__((ext_vector_type(4))) unsigned uint4v;

#define GLOAD_LDS16(gptr, lptr) \
    __builtin_amdgcn_global_load_lds((const __attribute__((address_space(1))) void*)(gptr), \
                                     (__attribute__((address_space(3))) void*)(lptr), 16, 0, 0)

__device__ __forceinline__ unsigned short f2b(float f) {
    union { float f; unsigned u; } v; v.f = f;
    unsigned r = v.u + 0x7fffu + ((v.u >> 16) & 1u);   // RNE
    return (unsigned short)(r >> 16);
}
__device__ __forceinline__ float blo(unsigned u) {
    union { unsigned u; float f; } v; v.u = u << 16; return v.f;
}
__device__ __forceinline__ float bhi(unsigned u) {
    union { unsigned u; float f; } v; v.u = u & 0xffff0000u; return v.f;
}

// ---------- fp32 -> bf16 bulk convert ----------
// x is written twice: slab-major xB[slice][node][32] (gather, L2-resident slices)
// and row-major xRow[node][128] (9th A slab for the GEMM).
__global__ void cvt_bf16_all(const float* __restrict__ x, long long nx,
                             const float* __restrict__ w, long long nw,
                             const float* __restrict__ root, long long nr,
                             unsigned short* __restrict__ xB,
                             unsigned short* __restrict__ xRow,
                             unsigned short* __restrict__ wB, int nN) {
    long long i = ((long long)blockIdx.x * blockDim.x + threadIdx.x) * 4;
    if (i < nx) {
        float4 v = *(const float4*)(x + i);
        uint2 p;
        p.x = (unsigned)f2b(v.x) | ((unsigned)f2b(v.y) << 16);
        p.y = (unsigned)f2b(v.z) | ((unsigned)f2b(v.w) << 16);
        long long n = i >> 7;
        int d = (int)(i & 127);
        size_t o = (size_t)(d >> 5) * (size_t)nN * 32 + (size_t)n * 32 + (d & 31);
        *(uint2*)(xB + o) = p;
        *(uint2*)(xRow + i) = p;
        return;
    }
    const float* src;
    unsigned short* dst;
    long long j;
    if (i < nx + nw) { src = w; dst = wB; j = i - nx; }
    else if (i < nx + nw + nr) { src = root; dst = wB + nw; j = i - nx - nw; }
    else return;
    float4 v = *(const float4*)(src + j);
    uint2 p;
    p.x = (unsigned)f2b(v.x) | ((unsigned)f2b(v.y) << 16);
    p.y = (unsigned)f2b(v.z) | ((unsigned)f2b(v.w) << 16);
    *(uint2*)(dst + j) = p;
}

// ---------- phase A: per-block bucket histogram (LDS atomics only) ----------
__global__ __launch_bounds__(256)
void histA(const int* __restrict__ ei, const int* __restrict__ et,
           int* __restrict__ blockHist, int nE, int nN, int B, int epb) {
    __shared__ int lh[1024];
    const int tid = threadIdx.x;
    for (int b = tid; b < B; b += 256) lh[b] = 0;
    __syncthreads();
    const int base = blockIdx.x * epb;
    const int lim = min(base + epb, nE);
    for (int e = base + tid; e < lim; e += 256) {
        int seg = et[e] * nN + ei[e];
        atomicAdd(&lh[seg >> SEG_BITS], 1);
    }
    __syncthreads();
    for (int b = tid; b < B; b += 256)
        blockHist[b * NBLK + blockIdx.x] = lh[b];
}

// ---------- scan of blockHist (bucket-major), 2 kernels + inline fixup ----------
__global__ __launch_bounds__(256)
void scan1(const int* __restrict__ in, int* __restrict__ excl,
           int* __restrict__ blockSums, int n) {
    __shared__ int t[256];
    const int tid = threadIdx.x;
    const int base = blockIdx.x * SCAN_CHUNK + tid * 8;
    int v[8];
    int tot = 0;
#pragma unroll
    for (int i = 0; i < 8; i++) {
        v[i] = (base + i < n) ? in[base + i] : 0;
        tot += v[i];
    }
    t[tid] = tot;
    __syncthreads();
    for (int off = 1; off < 256; off <<= 1) {
        int add = (tid >= off) ? t[tid - off] : 0;
        __syncthreads();
        t[tid] += add;
        __syncthreads();
    }
    int run = t[tid] - tot;
#pragma unroll
    for (int i = 0; i < 8; i++) {
        if (base + i < n) excl[base + i] = run;
        run += v[i];
    }
    if (tid == 255) blockSums[blockIdx.x] = t[255];
}

__global__ __launch_bounds__(256)
void scan2(int* __restrict__ blockSums, int nb) {
    __shared__ int t[256];
    const int tid = threadIdx.x;
    int v = (tid < nb) ? blockSums[tid] : 0;
    t[tid] = v;
    __syncthreads();
    for (int off = 1; off < 256; off <<= 1) {
        int add = (tid >= off) ? t[tid - off] : 0;
        __syncthreads();
        t[tid] += add;
        __syncthreads();
    }
    if (tid < nb) blockSums[tid] = t[tid] - v;
}

// ---------- phase C: bucket scatter (adds blockSums fix-up inline) ----------
__global__ __launch_bounds__(256)
void scatterA(const int* __restrict__ ei, const int* __restrict__ et,
              const int* __restrict__ scanned, const int* __restrict__ blockSums,
              unsigned* __restrict__ bucketEdges,
              int nE, int nN, int B, int epb) {
    __shared__ int cur[1024];
    const int tid = threadIdx.x;
    for (int b = tid; b < B; b += 256) {
        int idx = b * NBLK + blockIdx.x;
        cur[b] = scanned[idx] + blockSums[idx >> 11];   // SCAN_CHUNK = 2048
    }
    __syncthreads();
    const int base = blockIdx.x * epb;
    const int lim = min(base + epb, nE);
    for (int e = base + tid; e < lim; e += 256) {
        int seg = et[e] * nN + ei[e];
        int bkt = seg >> SEG_BITS;
        unsigned pk = ((unsigned)(seg & (SEGS_PER_BUCKET - 1)) << 16) | (unsigned)ei[nE + e];
        int pos = atomicAdd(&cur[bkt], 1);
        bucketEdges[pos] = pk;
    }
}

// ---------- phase D: per-bucket seg offsets + sorted ushort dst + local perm ----------
// Also builds the WINDOW-LOCAL degree-sorted permutation: perm[segBase+rank] = seg,
// rank = counting-sort rank by min(cnt,31) within this 512-seg window. Gather
// waves (16 consecutive perm entries) then see same-degree segments that are
// also CLOSE in memory (off/sortedDst stay within a ~4 KB window -> L2 streams).
__global__ __launch_bounds__(256)
void segOff(const unsigned* __restrict__ bucketEdges, const int* __restrict__ scanned,
            const int* __restrict__ blockSums,
            int* __restrict__ off, unsigned short* __restrict__ sortedDst,
            int* __restrict__ perm, int nE, int numSeg, int B) {
    __shared__ int lh[SEGS_PER_BUCKET];
    __shared__ int sc[256];
    __shared__ int lcur[SEGS_PER_BUCKET];
    __shared__ int dcnt[NDEG];
    __shared__ int dbase[NDEG];
    const int tid = threadIdx.x;
    const int b = blockIdx.x;
    const int i0 = b * NBLK;
    const int eBase = scanned[i0] + blockSums[i0 >> 11];
    int eEnd = nE;
    if (b + 1 < B) {
        const int i1 = (b + 1) * NBLK;
        eEnd = scanned[i1] + blockSums[i1 >> 11];
    }
    const int segBase = b * SEGS_PER_BUCKET;
    const int segLim = min(SEGS_PER_BUCKET, numSeg - segBase);

    lh[2 * tid] = 0; lh[2 * tid + 1] = 0;
    if (tid < NDEG) dcnt[tid] = 0;
    __syncthreads();
    for (int i = eBase + tid; i < eEnd; i += 256)
        atomicAdd(&lh[bucketEdges[i] >> 16], 1);
    __syncthreads();
    int a0 = lh[2 * tid], a1 = lh[2 * tid + 1];
    // window-local degree ranks
    int b0 = min(a0, NDEG - 1), b1 = min(a1, NDEG - 1), r0 = 0, r1 = 0;
    if (2 * tid < segLim)     r0 = atomicAdd(&dcnt[b0], 1);
    if (2 * tid + 1 < segLim) r1 = atomicAdd(&dcnt[b1], 1);
    sc[tid] = a0 + a1;
    __syncthreads();
    for (int o = 1; o < 256; o <<= 1) {
        int add = (tid >= o) ? sc[tid - o] : 0;
        __syncthreads();
        sc[tid] += add;
        __syncthreads();
    }
    int pairBase = sc[tid] - (a0 + a1);
    int g0 = eBase + pairBase;
    int g1 = g0 + a0;
    lcur[2 * tid] = g0;
    lcur[2 * tid + 1] = g1;
    if (2 * tid < segLim)     off[segBase + 2 * tid] = g0;
    if (2 * tid + 1 < segLim) off[segBase + 2 * tid + 1] = g1;
    if (b == B - 1 && tid == 0) off[numSeg] = nE;
    if (tid == 0) {               // serial 32-prefix for bucket bases
        int run = 0;
#pragma unroll
        for (int k = 0; k < NDEG; k++) { dbase[k] = run; run += dcnt[k]; }
    }
    __syncthreads();
    if (2 * tid < segLim)     perm[segBase + dbase[b0] + r0] = segBase + 2 * tid;
    if (2 * tid + 1 < segLim) perm[segBase + dbase[b1] + r1] = segBase + 2 * tid + 1;
    for (int i = eBase + tid; i < eEnd; i += 256) {
        unsigned u = bucketEdges[i];
        int pos = atomicAdd(&lcur[u >> 16], 1);
        sortedDst[pos] = (unsigned short)(u & 0xFFFFu);
    }
}

// ---------- gather: window-degree-binned, dim-sliced, 4 lanes/edge ----------
// blockIdx.y = slice (32 dims); per-slice xB slab = 3.2 MB -> per-XCD-L2 resident.
// Segments taken in perm order -> same-degree waves within a local window.
__global__ __launch_bounds__(256)
void rgcn_gather(const unsigned short* __restrict__ xB,
                 const unsigned short* __restrict__ sortedDst,
                 const int* __restrict__ off, const int* __restrict__ perm,
                 unsigned short* __restrict__ Abuf, int nN, int numSeg,
                 size_t SL, unsigned long long M) {
    const int tid = threadIdx.x;
    const int lane = tid & 63;
    const int idx4 = lane & 3;       // lane within 4-lane group (8 dims each)
    const int grp = lane >> 2;       // 16 groups per wave
    const int wv = tid >> 6;
    const int gsi = blockIdx.x * 64 + wv * 16 + grp;
    const int sl = blockIdx.y;       // dims [sl*32, sl*32+32)
    const bool valid = (gsi < numSeg);
    const int seg = valid ? perm[gsi] : 0;

    const int start = off[seg];
    int cnt = valid ? (off[seg + 1] - start) : 0;

    int mx = cnt;
    mx = max(mx, __shfl_xor(mx, 4));
    mx = max(mx, __shfl_xor(mx, 8));
    mx = max(mx, __shfl_xor(mx, 16));
    mx = max(mx, __shfl_xor(mx, 32));

    f32x2 acc2[4];
#pragma unroll
    for (int i = 0; i < 4; i++) acc2[i] = (f32x2){0.f, 0.f};

    // slab-major: xB[sl][node][32]; each lane owns 8 consecutive dims
    const unsigned short* xSlab = xB + (size_t)sl * nN * 32 + idx4 * 8;

    for (int b = 0; b < mx; b += 4) {
        int myDst = (b + idx4 < cnt) ? (int)sortedDst[start + b + idx4] : 0;
        uint4v v[4];
#pragma unroll
        for (int j = 0; j < 4; j++) {
            // batch 4 independent predicated loads (act uniform per group)
            int dst = __shfl(myDst, grp * 4 + j);
            bool act = (b + j < cnt);
            v[j] = act ? *(const uint4v*)(xSlab + ((size_t)dst << 5))
                       : (uint4v){0u, 0u, 0u, 0u};
        }
#pragma unroll
        for (int j = 0; j < 4; j++) {
            f32x2 t0 = (f32x2){blo(v[j].x), bhi(v[j].x)};
            f32x2 t1 = (f32x2){blo(v[j].y), bhi(v[j].y)};
            f32x2 t2 = (f32x2){blo(v[j].z), bhi(v[j].z)};
            f32x2 t3 = (f32x2){blo(v[j].w), bhi(v[j].w)};
            asm("v_pk_add_f32 %0, %0, %1" : "+v"(acc2[0]) : "v"(t0));
            asm("v_pk_add_f32 %0, %0, %1" : "+v"(acc2[1]) : "v"(t1));
            asm("v_pk_add_f32 %0, %0, %1" : "+v"(acc2[2]) : "v"(t2));
            asm("v_pk_add_f32 %0, %0, %1" : "+v"(acc2[3]) : "v"(t3));
        }
    }

    if (valid) {
        const int r = (int)(((unsigned long long)seg * M) >> 48);  // seg / nN
        const int n = seg - r * nN;
        float s = cnt > 0 ? 1.0f / (float)cnt : 0.f;
        uint4v pkt;
        pkt.x = (unsigned)f2b(acc2[0].x * s) | ((unsigned)f2b(acc2[0].y * s) << 16);
        pkt.y = (unsigned)f2b(acc2[1].x * s) | ((unsigned)f2b(acc2[1].y * s) << 16);
        pkt.z = (unsigned)f2b(acc2[2].x * s) | ((unsigned)f2b(acc2[2].y * s) << 16);
        pkt.w = (unsigned)f2b(acc2[3].x * s) | ((unsigned)f2b(acc2[3].y * s) << 16);
        // nt store (64B sectors, no amplification — WRITE_SIZE was exact in R2)
        __builtin_nontemporal_store(pkt,
            (uint4v*)(Abuf + (size_t)r * SL + (size_t)n * D + sl * 32 + idx4 * 8));
    }
}

// ---------- MFMA GEMM: M=nN, N=128, K=(nRel+1)*128 ----------
// A = [nRel+1][nNalloc][128] contiguous (8 agg slabs + xRow); B = wB [nRel+1][128][128].
// Pipelined 2-phase: global_load_lds(16B) into linear LDS, st_8x16 XOR swizzle
// applied on the global SOURCE address; ds_read applies the same XOR. 1 barrier/step.
__global__ __launch_bounds__(256)
void rgcn_gemm_mfma(const unsigned short* __restrict__ A,
                    const unsigned short* __restrict__ wB,
                    const float* __restrict__ bias,
                    float* __restrict__ out, int nN, int nRel, size_t SL) {
    __shared__ __align__(16) unsigned short As[2][64 * 64];    // [buf][row][64k]
    __shared__ __align__(16) unsigned short Bs[2][128 * 64];   // [buf][ocol][64k]
    const int tid = threadIdx.x;
    const int wave = tid >> 6;
    const int lane = tid & 63;
    const int wm = wave & 1;
    const int wn = wave >> 1;
    const int m16 = lane & 15;
    const int q = lane >> 4;
    const int row0 = blockIdx.x * 64;

    v4f acc[2][4];
#pragma unroll
    for (int i = 0; i < 2; i++)
#pragma unroll
        for (int j = 0; j < 4; j++) acc[i][j] = (v4f){0.f, 0.f, 0.f, 0.f};

    // ds_read offsets (ushort idx), swizzle: granule g read at slot g ^ (row&7);
    // row&7 == m16&7 for all frags (row/ocol = mult-of-8 + m16).
    const int sw = m16 & 7;
    int aoff[2][2], boff[4][2];
#pragma unroll
    for (int mt = 0; mt < 2; mt++) {
        int row = wm * 32 + mt * 16 + m16;
#pragma unroll
        for (int kb = 0; kb < 2; kb++)
            aoff[mt][kb] = row * 64 + (((kb * 4 + q) ^ sw) * 8);
    }
#pragma unroll
    for (int nt = 0; nt < 4; nt++) {
        int o = wn * 64 + nt * 16 + m16;
#pragma unroll
        for (int kb = 0; kb < 2; kb++)
            boff[nt][kb] = o * 64 + (((kb * 4 + q) ^ sw) * 8);
    }

    // staging: lane l of issue i writes LDS slot (base_i + l); slot -> row=slot>>3,
    // gs=slot&7; source granule gd = gs ^ (row&7) = (l&7) ^ (l>>3) (i adds 8 rows).
    const int l8 = lane >> 3;
    const int gd = (lane & 7) ^ l8;
    const size_t aBase = (size_t)(row0 + wave * 16 + l8) * D + gd * 8;  // elements
    const size_t bBase = (size_t)(wave * 32 + l8) * D + gd * 8;

    const int nT = 2 * (nRel + 1);    // 18 K-steps of 64

#define STAGE(buf, t) do { \
        const int s_ = (t) >> 1, h_ = (t) & 1; \
        const unsigned short* ga_ = A + (size_t)s_ * SL + h_ * 64 + aBase; \
        const unsigned short* gb_ = wB + (size_t)s_ * (D * D) + h_ * 64 + bBase; \
        GLOAD_LDS16(ga_,        &As[buf][(wave * 2 + 0) * 512]); \
        GLOAD_LDS16(ga_ + 1024, &As[buf][(wave * 2 + 1) * 512]); \
        GLOAD_LDS16(gb_,        &Bs[buf][(wave * 4 + 0) * 512]); \
        GLOAD_LDS16(gb_ + 1024, &Bs[buf][(wave * 4 + 1) * 512]); \
        GLOAD_LDS16(gb_ + 2048, &Bs[buf][(wave * 4 + 2) * 512]); \
        GLOAD_LDS16(gb_ + 3072, &Bs[buf][(wave * 4 + 3) * 512]); \
    } while (0)

    STAGE(0, 0);
    __syncthreads();                    // vmcnt(0) drain emitted by compiler
    int cur = 0;
    for (int t = 0; t < nT; ++t) {
        if (t + 1 < nT) STAGE(cur ^ 1, t + 1);   // next tile in flight over compute
        const unsigned short* Ab = As[cur];
        const unsigned short* Bb = Bs[cur];
        short8 a[2][2], b[4][2];
#pragma unroll
        for (int kb = 0; kb < 2; kb++) {
#pragma unroll
            for (int mt = 0; mt < 2; mt++)
                a[mt][kb] = *(const short8*)&Ab[aoff[mt][kb]];
#pragma unroll
            for (int nt = 0; nt < 4; nt++)
                b[nt][kb] = *(const short8*)&Bb[boff[nt][kb]];
        }
#pragma unroll
        for (int kb = 0; kb < 2; kb++)
#pragma unroll
            for (int mt = 0; mt < 2; mt++)
#pragma unroll
                for (int nt = 0; nt < 4; nt++)
                    acc[mt][nt] = __builtin_amdgcn_mfma_f32_16x16x32_bf16(
                        a[mt][kb], b[nt][kb], acc[mt][nt], 0, 0, 0);
        __syncthreads();
        cur ^= 1;
    }
#undef STAGE

#pragma unroll
    for (int mt = 0; mt < 2; mt++) {
#pragma unroll
        for (int nt = 0; nt < 4; nt++) {
            int col = wn * 64 + nt * 16 + m16;
            float bi = bias[col];
#pragma unroll
            for (int reg = 0; reg < 4; reg++) {
                int rrow = row0 + wm * 32 + mt * 16 + q * 4 + reg;
                if (rrow < nN)
                    out[(size_t)rrow * D + col] = acc[mt][nt][reg] + bi;
            }
        }
    }
}

extern "C" void kernel_launch(void* const* d_in, const int* in_sizes, int n_in,
                              void* d_out, int out_size, void* d_ws, size_t ws_size,
                              hipStream_t stream) {
    const float* x    = (const float*)d_in[0];
    const int*   ei   = (const int*)d_in[1];
    const int*   et   = (const int*)d_in[2];
    const float* w    = (const float*)d_in[3];
    const float* root = (const float*)d_in[4];
    const float* bias = (const float*)d_in[5];
    float* out = (float*)d_out;

    const int nN   = in_sizes[0] / D;        // 50000 (< 65536 for ushort dst)
    const int nE   = in_sizes[2];
    const int nRel = in_sizes[3] / (D * D);
    const int numSeg = nRel * nN;
    const int B = (numSeg + SEGS_PER_BUCKET - 1) >> SEG_BITS;   // 782 (<= 1024)
    const int nBH = B * NBLK;
    const int epb = (nE + NBLK - 1) / NBLK;
    const int nNalloc = (nN + 63) & ~63;     // pad rows to 64; garbage rows benign
    const size_t SL = (size_t)nNalloc * D;   // elements per A slab
    const unsigned long long M = ((1ULL << 48) + nN - 1) / nN;  // magic for /nN

    // workspace layout (~157 MB; ws proven >= 218 MB in round 4)
    char* p = (char*)d_ws;
    unsigned* bucketEdges   = (unsigned*)p;        p += (size_t)nE * sizeof(unsigned);
    unsigned short* sortedDst = (unsigned short*)p; p += (size_t)nE * sizeof(unsigned short);
    p = (char*)(((uintptr_t)p + 255) & ~(uintptr_t)255);
    int* off       = (int*)p;  p += (size_t)(numSeg + 1) * sizeof(int);
    int* blockHist = (int*)p;  p += (size_t)nBH * sizeof(int);
    int* scanned   = (int*)p;  p += (size_t)nBH * sizeof(int);
    int* blockSums = (int*)p;  p += 256 * sizeof(int);
    p = (char*)(((uintptr_t)p + 255) & ~(uintptr_t)255);
    int* perm      = (int*)p;  p += (size_t)numSeg * sizeof(int);
    p = (char*)(((uintptr_t)p + 255) & ~(uintptr_t)255);
    unsigned short* xB   = (unsigned short*)p;  p += (size_t)nN * D * sizeof(unsigned short);
    unsigned short* wBc  = (unsigned short*)p;  p += (size_t)(nRel + 1) * D * D * sizeof(unsigned short);
    p = (char*)(((uintptr_t)p + 255) & ~(uintptr_t)255);
    unsigned short* Abuf = (unsigned short*)p;     // [nRel+1][nNalloc][128]
    unsigned short* xRow = Abuf + (size_t)nRel * SL;

    const int nScanBlocks = (nBH + SCAN_CHUNK - 1) / SCAN_CHUNK;  // 49 <= 256

    histA<<<NBLK, 256, 0, stream>>>(ei, et, blockHist, nE, nN, B, epb);
    scan1<<<nScanBlocks, 256, 0, stream>>>(blockHist, scanned, blockSums, nBH);
    scan2<<<1, 256, 0, stream>>>(blockSums, nScanBlocks);
    scatterA<<<NBLK, 256, 0, stream>>>(ei, et, scanned, blockSums, bucketEdges, nE, nN, B, epb);
    segOff<<<B, 256, 0, stream>>>(bucketEdges, scanned, blockSums, off, sortedDst, perm,
                                  nE, numSeg, B);

    long long nx = (long long)nN * D;
    long long nw = (long long)nRel * D * D;
    long long nr = (long long)D * D;
    long long ncvt = (nx + nw + nr) / 4;
    cvt_bf16_all<<<(int)((ncvt + 255) / 256), 256, 0, stream>>>(x, nx, w, nw, root, nr,
                                                                xB, xRow, wBc, nN);

    dim3 gg((numSeg + 63) / 64, 4);
    rgcn_gather<<<gg, 256, 0, stream>>>(xB, sortedDst, off, perm, Abuf, nN, numSeg, SL, M);

    rgcn_gemm_mfma<<<(nN + 63) / 64, 256, 0, stream>>>(Abuf, wBc, bias, out, nN, nRel, SL);
}

// Round 5
// 269.070 us; speedup vs baseline: 1.1235x; 1.0759x over previous
//
#include <hip/hip_runtime.h>

// RGCN: bucketed atomic-free counting sort + block-local degree-binned
// dim-sliced bf16 gather + pipelined bf16 MFMA GEMM.
// Round-15:
//   - degree binning now at 64-SEG (one gather block) granularity, built in
//     segOff with 8x32 LDS counters. R3/R4's 512-window perm made every
//     gather block read the whole window's sortedDst/off -> fetched by up
//     to 8 different XCD L2s (FETCH 66->157 MB). Block-local perm restores
//     R2's private contiguous reads while keeping same-degree waves
//     (inner-loop padding ~0.6x of unsorted).
//   - keeps: v_pk_add_f32 accumulate, magic-div r recovery, dim-sliced gather,
//     pipelined global_load_lds GEMM
//
//   seg(e) = rel(e)*nN + src(e)          (numSeg = nRel*nN)
//   agg[seg,:] = bf16( mean_{e in seg} x[dst_e,:] )
//   out = sum_r agg_r @ W_r^T + x @ root^T + bias   (MFMA 16x16x32 bf16)

#define D 128
#define SCAN_CHUNK 2048
#define SEG_BITS 9
#define SEGS_PER_BUCKET 512
#define NBLK 128            // blocks for histA/scatterA
#define NDEG 32             // degree buckets

typedef __attribute__((ext_vector_type(8))) short short8;
typedef __attribute__((ext_vector_type(4))) float v4f;
typedef __attribute__((ext_vector_type(2))) float f32x2;
typedef __attribute__((ext_vector_type(4))) unsigned uint4v;

#define GLOAD_LDS16(gptr, lptr) \
    __builtin_amdgcn_global_load_lds((const __attribute__((address_space(1))) void*)(gptr), \
                                     (__attribute__((address_space(3))) void*)(lptr), 16, 0, 0)

__device__ __forceinline__ unsigned short f2b(float f) {
    union { float f; unsigned u; } v; v.f = f;
    unsigned r = v.u + 0x7fffu + ((v.u >> 16) & 1u);   // RNE
    return (unsigned short)(r >> 16);
}
__device__ __forceinline__ float blo(unsigned u) {
    union { unsigned u; float f; } v; v.u = u << 16; return v.f;
}
__device__ __forceinline__ float bhi(unsigned u) {
    union { unsigned u; float f; } v; v.u = u & 0xffff0000u; return v.f;
}

// ---------- fp32 -> bf16 bulk convert ----------
// x is written twice: slab-major xB[slice][node][32] (gather, L2-resident slices)
// and row-major xRow[node][128] (9th A slab for the GEMM).
__global__ void cvt_bf16_all(const float* __restrict__ x, long long nx,
                             const float* __restrict__ w, long long nw,
                             const float* __restrict__ root, long long nr,
                             unsigned short* __restrict__ xB,
                             unsigned short* __restrict__ xRow,
                             unsigned short* __restrict__ wB, int nN) {
    long long i = ((long long)blockIdx.x * blockDim.x + threadIdx.x) * 4;
    if (i < nx) {
        float4 v = *(const float4*)(x + i);
        uint2 p;
        p.x = (unsigned)f2b(v.x) | ((unsigned)f2b(v.y) << 16);
        p.y = (unsigned)f2b(v.z) | ((unsigned)f2b(v.w) << 16);
        long long n = i >> 7;
        int d = (int)(i & 127);
        size_t o = (size_t)(d >> 5) * (size_t)nN * 32 + (size_t)n * 32 + (d & 31);
        *(uint2*)(xB + o) = p;
        *(uint2*)(xRow + i) = p;
        return;
    }
    const float* src;
    unsigned short* dst;
    long long j;
    if (i < nx + nw) { src = w; dst = wB; j = i - nx; }
    else if (i < nx + nw + nr) { src = root; dst = wB + nw; j = i - nx - nw; }
    else return;
    float4 v = *(const float4*)(src + j);
    uint2 p;
    p.x = (unsigned)f2b(v.x) | ((unsigned)f2b(v.y) << 16);
    p.y = (unsigned)f2b(v.z) | ((unsigned)f2b(v.w) << 16);
    *(uint2*)(dst + j) = p;
}

// ---------- phase A: per-block bucket histogram (LDS atomics only) ----------
__global__ __launch_bounds__(256)
void histA(const int* __restrict__ ei, const int* __restrict__ et,
           int* __restrict__ blockHist, int nE, int nN, int B, int epb) {
    __shared__ int lh[1024];
    const int tid = threadIdx.x;
    for (int b = tid; b < B; b += 256) lh[b] = 0;
    __syncthreads();
    const int base = blockIdx.x * epb;
    const int lim = min(base + epb, nE);
    for (int e = base + tid; e < lim; e += 256) {
        int seg = et[e] * nN + ei[e];
        atomicAdd(&lh[seg >> SEG_BITS], 1);
    }
    __syncthreads();
    for (int b = tid; b < B; b += 256)
        blockHist[b * NBLK + blockIdx.x] = lh[b];
}

// ---------- scan of blockHist (bucket-major), 2 kernels + inline fixup ----------
__global__ __launch_bounds__(256)
void scan1(const int* __restrict__ in, int* __restrict__ excl,
           int* __restrict__ blockSums, int n) {
    __shared__ int t[256];
    const int tid = threadIdx.x;
    const int base = blockIdx.x * SCAN_CHUNK + tid * 8;
    int v[8];
    int tot = 0;
#pragma unroll
    for (int i = 0; i < 8; i++) {
        v[i] = (base + i < n) ? in[base + i] : 0;
        tot += v[i];
    }
    t[tid] = tot;
    __syncthreads();
    for (int off = 1; off < 256; off <<= 1) {
        int add = (tid >= off) ? t[tid - off] : 0;
        __syncthreads();
        t[tid] += add;
        __syncthreads();
    }
    int run = t[tid] - tot;
#pragma unroll
    for (int i = 0; i < 8; i++) {
        if (base + i < n) excl[base + i] = run;
        run += v[i];
    }
    if (tid == 255) blockSums[blockIdx.x] = t[255];
}

__global__ __launch_bounds__(256)
void scan2(int* __restrict__ blockSums, int nb) {
    __shared__ int t[256];
    const int tid = threadIdx.x;
    int v = (tid < nb) ? blockSums[tid] : 0;
    t[tid] = v;
    __syncthreads();
    for (int off = 1; off < 256; off <<= 1) {
        int add = (tid >= off) ? t[tid - off] : 0;
        __syncthreads();
        t[tid] += add;
        __syncthreads();
    }
    if (tid < nb) blockSums[tid] = t[tid] - v;
}

// ---------- phase C: bucket scatter (adds blockSums fix-up inline) ----------
__global__ __launch_bounds__(256)
void scatterA(const int* __restrict__ ei, const int* __restrict__ et,
              const int* __restrict__ scanned, const int* __restrict__ blockSums,
              unsigned* __restrict__ bucketEdges,
              int nE, int nN, int B, int epb) {
    __shared__ int cur[1024];
    const int tid = threadIdx.x;
    for (int b = tid; b < B; b += 256) {
        int idx = b * NBLK + blockIdx.x;
        cur[b] = scanned[idx] + blockSums[idx >> 11];   // SCAN_CHUNK = 2048
    }
    __syncthreads();
    const int base = blockIdx.x * epb;
    const int lim = min(base + epb, nE);
    for (int e = base + tid; e < lim; e += 256) {
        int seg = et[e] * nN + ei[e];
        int bkt = seg >> SEG_BITS;
        unsigned pk = ((unsigned)(seg & (SEGS_PER_BUCKET - 1)) << 16) | (unsigned)ei[nE + e];
        int pos = atomicAdd(&cur[bkt], 1);
        bucketEdges[pos] = pk;
    }
}

// ---------- phase D: per-bucket seg offsets + sorted ushort dst + local perm ----------
// Builds the BLOCK-LOCAL degree-sorted permutation: within each 64-seg
// sub-window (= one gather block), perm[...] = segs ranked by min(cnt,31).
// Gather block b then reads only its own contiguous 512 B of sortedDst and
// 260 B of off (no cross-XCD sharing), while its 4 waves see same-degree segs.
__global__ __launch_bounds__(256)
void segOff(const unsigned* __restrict__ bucketEdges, const int* __restrict__ scanned,
            const int* __restrict__ blockSums,
            int* __restrict__ off, unsigned short* __restrict__ sortedDst,
            int* __restrict__ perm, int nE, int numSeg, int B) {
    __shared__ int lh[SEGS_PER_BUCKET];
    __shared__ int sc[256];
    __shared__ int lcur[SEGS_PER_BUCKET];
    __shared__ int dcnt[256];    // [sub 0..7][deg 0..31]
    __shared__ int dbase[256];
    const int tid = threadIdx.x;
    const int b = blockIdx.x;
    const int i0 = b * NBLK;
    const int eBase = scanned[i0] + blockSums[i0 >> 11];
    int eEnd = nE;
    if (b + 1 < B) {
        const int i1 = (b + 1) * NBLK;
        eEnd = scanned[i1] + blockSums[i1 >> 11];
    }
    const int segBase = b * SEGS_PER_BUCKET;
    const int segLim = min(SEGS_PER_BUCKET, numSeg - segBase);

    lh[2 * tid] = 0; lh[2 * tid + 1] = 0;
    dcnt[tid] = 0;
    __syncthreads();
    for (int i = eBase + tid; i < eEnd; i += 256)
        atomicAdd(&lh[bucketEdges[i] >> 16], 1);
    __syncthreads();
    const int li0 = 2 * tid, li1 = 2 * tid + 1;
    const int sub = li0 >> 6;            // 64-seg sub-window (== li1>>6)
    int a0 = lh[li0], a1 = lh[li1];
    // block-local degree ranks (within the 64-seg sub-window)
    int b0 = min(a0, NDEG - 1), b1 = min(a1, NDEG - 1), r0 = 0, r1 = 0;
    if (li0 < segLim) r0 = atomicAdd(&dcnt[sub * NDEG + b0], 1);
    if (li1 < segLim) r1 = atomicAdd(&dcnt[sub * NDEG + b1], 1);
    sc[tid] = a0 + a1;
    __syncthreads();
    for (int o = 1; o < 256; o <<= 1) {
        int add = (tid >= o) ? sc[tid - o] : 0;
        __syncthreads();
        sc[tid] += add;
        __syncthreads();
    }
    int pairBase = sc[tid] - (a0 + a1);
    int g0 = eBase + pairBase;
    int g1 = g0 + a0;
    lcur[li0] = g0;
    lcur[li1] = g1;
    if (li0 < segLim) off[segBase + li0] = g0;
    if (li1 < segLim) off[segBase + li1] = g1;
    if (b == B - 1 && tid == 0) off[numSeg] = nE;
    if (tid < 8) {               // per-sub serial 32-prefix for bucket bases
        int run = 0;
#pragma unroll
        for (int k = 0; k < NDEG; k++) { dbase[tid * NDEG + k] = run; run += dcnt[tid * NDEG + k]; }
    }
    __syncthreads();
    if (li0 < segLim) perm[segBase + sub * 64 + dbase[sub * NDEG + b0] + r0] = segBase + li0;
    if (li1 < segLim) perm[segBase + sub * 64 + dbase[sub * NDEG + b1] + r1] = segBase + li1;
    for (int i = eBase + tid; i < eEnd; i += 256) {
        unsigned u = bucketEdges[i];
        int pos = atomicAdd(&lcur[u >> 16], 1);
        sortedDst[pos] = (unsigned short)(u & 0xFFFFu);
    }
}

// ---------- gather: block-degree-binned, dim-sliced, 4 lanes/edge ----------
// blockIdx.y = slice (32 dims); per-slice xB slab = 3.2 MB -> per-XCD-L2 resident.
// perm permutes only within each block's 64 segs -> block-private reads.
__global__ __launch_bounds__(256)
void rgcn_gather(const unsigned short* __restrict__ xB,
                 const unsigned short* __restrict__ sortedDst,
                 const int* __restrict__ off, const int* __restrict__ perm,
                 unsigned short* __restrict__ Abuf, int nN, int numSeg,
                 size_t SL, unsigned long long M) {
    const int tid = threadIdx.x;
    const int lane = tid & 63;
    const int idx4 = lane & 3;       // lane within 4-lane group (8 dims each)
    const int grp = lane >> 2;       // 16 groups per wave
    const int wv = tid >> 6;
    const int gsi = blockIdx.x * 64 + wv * 16 + grp;
    const int sl = blockIdx.y;       // dims [sl*32, sl*32+32)
    const bool valid = (gsi < numSeg);
    const int seg = valid ? perm[gsi] : 0;

    const int start = off[seg];
    int cnt = valid ? (off[seg + 1] - start) : 0;

    int mx = cnt;
    mx = max(mx, __shfl_xor(mx, 4));
    mx = max(mx, __shfl_xor(mx, 8));
    mx = max(mx, __shfl_xor(mx, 16));
    mx = max(mx, __shfl_xor(mx, 32));

    f32x2 acc2[4];
#pragma unroll
    for (int i = 0; i < 4; i++) acc2[i] = (f32x2){0.f, 0.f};

    // slab-major: xB[sl][node][32]; each lane owns 8 consecutive dims
    const unsigned short* xSlab = xB + (size_t)sl * nN * 32 + idx4 * 8;

    for (int b = 0; b < mx; b += 4) {
        int myDst = (b + idx4 < cnt) ? (int)sortedDst[start + b + idx4] : 0;
        uint4v v[4];
#pragma unroll
        for (int j = 0; j < 4; j++) {
            // batch 4 independent predicated loads (act uniform per group)
            int dst = __shfl(myDst, grp * 4 + j);
            bool act = (b + j < cnt);
            v[j] = act ? *(const uint4v*)(xSlab + ((size_t)dst << 5))
                       : (uint4v){0u, 0u, 0u, 0u};
        }
#pragma unroll
        for (int j = 0; j < 4; j++) {
            f32x2 t0 = (f32x2){blo(v[j].x), bhi(v[j].x)};
            f32x2 t1 = (f32x2){blo(v[j].y), bhi(v[j].y)};
            f32x2 t2 = (f32x2){blo(v[j].z), bhi(v[j].z)};
            f32x2 t3 = (f32x2){blo(v[j].w), bhi(v[j].w)};
            asm("v_pk_add_f32 %0, %0, %1" : "+v"(acc2[0]) : "v"(t0));
            asm("v_pk_add_f32 %0, %0, %1" : "+v"(acc2[1]) : "v"(t1));
            asm("v_pk_add_f32 %0, %0, %1" : "+v"(acc2[2]) : "v"(t2));
            asm("v_pk_add_f32 %0, %0, %1" : "+v"(acc2[3]) : "v"(t3));
        }
    }

    if (valid) {
        const int r = (int)(((unsigned long long)seg * M) >> 48);  // seg / nN
        const int n = seg - r * nN;
        float s = cnt > 0 ? 1.0f / (float)cnt : 0.f;
        uint4v pkt;
        pkt.x = (unsigned)f2b(acc2[0].x * s) | ((unsigned)f2b(acc2[0].y * s) << 16);
        pkt.y = (unsigned)f2b(acc2[1].x * s) | ((unsigned)f2b(acc2[1].y * s) << 16);
        pkt.z = (unsigned)f2b(acc2[2].x * s) | ((unsigned)f2b(acc2[2].y * s) << 16);
        pkt.w = (unsigned)f2b(acc2[3].x * s) | ((unsigned)f2b(acc2[3].y * s) << 16);
        // nt store (64B sectors, no amplification — WRITE_SIZE was exact in R2)
        __builtin_nontemporal_store(pkt,
            (uint4v*)(Abuf + (size_t)r * SL + (size_t)n * D + sl * 32 + idx4 * 8));
    }
}

// ---------- MFMA GEMM: M=nN, N=128, K=(nRel+1)*128 ----------
// A = [nRel+1][nNalloc][128] contiguous (8 agg slabs + xRow); B = wB [nRel+1][128][128].
// Pipelined 2-phase: global_load_lds(16B) into linear LDS, st_8x16 XOR swizzle
// applied on the global SOURCE address; ds_read applies the same XOR. 1 barrier/step.
__global__ __launch_bounds__(256)
void rgcn_gemm_mfma(const unsigned short* __restrict__ A,
                    const unsigned short* __restrict__ wB,
                    const float* __restrict__ bias,
                    float* __restrict__ out, int nN, int nRel, size_t SL) {
    __shared__ __align__(16) unsigned short As[2][64 * 64];    // [buf][row][64k]
    __shared__ __align__(16) unsigned short Bs[2][128 * 64];   // [buf][ocol][64k]
    const int tid = threadIdx.x;
    const int wave = tid >> 6;
    const int lane = tid & 63;
    const int wm = wave & 1;
    const int wn = wave >> 1;
    const int m16 = lane & 15;
    const int q = lane >> 4;
    const int row0 = blockIdx.x * 64;

    v4f acc[2][4];
#pragma unroll
    for (int i = 0; i < 2; i++)
#pragma unroll
        for (int j = 0; j < 4; j++) acc[i][j] = (v4f){0.f, 0.f, 0.f, 0.f};

    // ds_read offsets (ushort idx), swizzle: granule g read at slot g ^ (row&7);
    // row&7 == m16&7 for all frags (row/ocol = mult-of-8 + m16).
    const int sw = m16 & 7;
    int aoff[2][2], boff[4][2];
#pragma unroll
    for (int mt = 0; mt < 2; mt++) {
        int row = wm * 32 + mt * 16 + m16;
#pragma unroll
        for (int kb = 0; kb < 2; kb++)
            aoff[mt][kb] = row * 64 + (((kb * 4 + q) ^ sw) * 8);
    }
#pragma unroll
    for (int nt = 0; nt < 4; nt++) {
        int o = wn * 64 + nt * 16 + m16;
#pragma unroll
        for (int kb = 0; kb < 2; kb++)
            boff[nt][kb] = o * 64 + (((kb * 4 + q) ^ sw) * 8);
    }

    // staging: lane l of issue i writes LDS slot (base_i + l); slot -> row=slot>>3,
    // gs=slot&7; source granule gd = gs ^ (row&7) = (l&7) ^ (l>>3) (i adds 8 rows).
    const int l8 = lane >> 3;
    const int gd = (lane & 7) ^ l8;
    const size_t aBase = (size_t)(row0 + wave * 16 + l8) * D + gd * 8;  // elements
    const size_t bBase = (size_t)(wave * 32 + l8) * D + gd * 8;

    const int nT = 2 * (nRel + 1);    // 18 K-steps of 64

#define STAGE(buf, t) do { \
        const int s_ = (t) >> 1, h_ = (t) & 1; \
        const unsigned short* ga_ = A + (size_t)s_ * SL + h_ * 64 + aBase; \
        const unsigned short* gb_ = wB + (size_t)s_ * (D * D) + h_ * 64 + bBase; \
        GLOAD_LDS16(ga_,        &As[buf][(wave * 2 + 0) * 512]); \
        GLOAD_LDS16(ga_ + 1024, &As[buf][(wave * 2 + 1) * 512]); \
        GLOAD_LDS16(gb_,        &Bs[buf][(wave * 4 + 0) * 512]); \
        GLOAD_LDS16(gb_ + 1024, &Bs[buf][(wave * 4 + 1) * 512]); \
        GLOAD_LDS16(gb_ + 2048, &Bs[buf][(wave * 4 + 2) * 512]); \
        GLOAD_LDS16(gb_ + 3072, &Bs[buf][(wave * 4 + 3) * 512]); \
    } while (0)

    STAGE(0, 0);
    __syncthreads();                    // vmcnt(0) drain emitted by compiler
    int cur = 0;
    for (int t = 0; t < nT; ++t) {
        if (t + 1 < nT) STAGE(cur ^ 1, t + 1);   // next tile in flight over compute
        const unsigned short* Ab = As[cur];
        const unsigned short* Bb = Bs[cur];
        short8 a[2][2], b[4][2];
#pragma unroll
        for (int kb = 0; kb < 2; kb++) {
#pragma unroll
            for (int mt = 0; mt < 2; mt++)
                a[mt][kb] = *(const short8*)&Ab[aoff[mt][kb]];
#pragma unroll
            for (int nt = 0; nt < 4; nt++)
                b[nt][kb] = *(const short8*)&Bb[boff[nt][kb]];
        }
#pragma unroll
        for (int kb = 0; kb < 2; kb++)
#pragma unroll
            for (int mt = 0; mt < 2; mt++)
#pragma unroll
                for (int nt = 0; nt < 4; nt++)
                    acc[mt][nt] = __builtin_amdgcn_mfma_f32_16x16x32_bf16(
                        a[mt][kb], b[nt][kb], acc[mt][nt], 0, 0, 0);
        __syncthreads();
        cur ^= 1;
    }
#undef STAGE

#pragma unroll
    for (int mt = 0; mt < 2; mt++) {
#pragma unroll
        for (int nt = 0; nt < 4; nt++) {
            int col = wn * 64 + nt * 16 + m16;
            float bi = bias[col];
#pragma unroll
            for (int reg = 0; reg < 4; reg++) {
                int rrow = row0 + wm * 32 + mt * 16 + q * 4 + reg;
                if (rrow < nN)
                    out[(size_t)rrow * D + col] = acc[mt][nt][reg] + bi;
            }
        }
    }
}

extern "C" void kernel_launch(void* const* d_in, const int* in_sizes, int n_in,
                              void* d_out, int out_size, void* d_ws, size_t ws_size,
                              hipStream_t stream) {
    const float* x    = (const float*)d_in[0];
    const int*   ei   = (const int*)d_in[1];
    const int*   et   = (const int*)d_in[2];
    const float* w    = (const float*)d_in[3];
    const float* root = (const float*)d_in[4];
    const float* bias = (const float*)d_in[5];
    float* out = (float*)d_out;

    const int nN   = in_sizes[0] / D;        // 50000 (< 65536 for ushort dst)
    const int nE   = in_sizes[2];
    const int nRel = in_sizes[3] / (D * D);
    const int numSeg = nRel * nN;
    const int B = (numSeg + SEGS_PER_BUCKET - 1) >> SEG_BITS;   // 782 (<= 1024)
    const int nBH = B * NBLK;
    const int epb = (nE + NBLK - 1) / NBLK;
    const int nNalloc = (nN + 63) & ~63;     // pad rows to 64; garbage rows benign
    const size_t SL = (size_t)nNalloc * D;   // elements per A slab
    const unsigned long long M = ((1ULL << 48) + nN - 1) / nN;  // magic for /nN

    // workspace layout (~157 MB; ws proven >= 218 MB in round 4)
    char* p = (char*)d_ws;
    unsigned* bucketEdges   = (unsigned*)p;        p += (size_t)nE * sizeof(unsigned);
    unsigned short* sortedDst = (unsigned short*)p; p += (size_t)nE * sizeof(unsigned short);
    p = (char*)(((uintptr_t)p + 255) & ~(uintptr_t)255);
    int* off       = (int*)p;  p += (size_t)(numSeg + 1) * sizeof(int);
    int* blockHist = (int*)p;  p += (size_t)nBH * sizeof(int);
    int* scanned   = (int*)p;  p += (size_t)nBH * sizeof(int);
    int* blockSums = (int*)p;  p += 256 * sizeof(int);
    p = (char*)(((uintptr_t)p + 255) & ~(uintptr_t)255);
    int* perm      = (int*)p;  p += (size_t)numSeg * sizeof(int);
    p = (char*)(((uintptr_t)p + 255) & ~(uintptr_t)255);
    unsigned short* xB   = (unsigned short*)p;  p += (size_t)nN * D * sizeof(unsigned short);
    unsigned short* wBc  = (unsigned short*)p;  p += (size_t)(nRel + 1) * D * D * sizeof(unsigned short);
    p = (char*)(((uintptr_t)p + 255) & ~(uintptr_t)255);
    unsigned short* Abuf = (unsigned short*)p;     // [nRel+1][nNalloc][128]
    unsigned short* xRow = Abuf + (size_t)nRel * SL;

    const int nScanBlocks = (nBH + SCAN_CHUNK - 1) / SCAN_CHUNK;  // 49 <= 256

    histA<<<NBLK, 256, 0, stream>>>(ei, et, blockHist, nE, nN, B, epb);
    scan1<<<nScanBlocks, 256, 0, stream>>>(blockHist, scanned, blockSums, nBH);
    scan2<<<1, 256, 0, stream>>>(blockSums, nScanBlocks);
    scatterA<<<NBLK, 256, 0, stream>>>(ei, et, scanned, blockSums, bucketEdges, nE, nN, B, epb);
    segOff<<<B, 256, 0, stream>>>(bucketEdges, scanned, blockSums, off, sortedDst, perm,
                                  nE, numSeg, B);

    long long nx = (long long)nN * D;
    long long nw = (long long)nRel * D * D;
    long long nr = (long long)D * D;
    long long ncvt = (nx + nw + nr) / 4;
    cvt_bf16_all<<<(int)((ncvt + 255) / 256), 256, 0, stream>>>(x, nx, w, nw, root, nr,
                                                                xB, xRow, wBc, nN);

    dim3 gg((numSeg + 63) / 64, 4);
    rgcn_gather<<<gg, 256, 0, stream>>>(xB, sortedDst, off, perm, Abuf, nN, numSeg, SL, M);

    rgcn_gemm_mfma<<<(nN + 63) / 64, 256, 0, stream>>>(Abuf, wBc, bias, out, nN, nRel, SL);
}

// Round 6
// 268.042 us; speedup vs baseline: 1.1278x; 1.0038x over previous
//
#include <hip/hip_runtime.h>

// RGCN: bucketed atomic-free counting sort + block-local degree-binned
// dim-sliced bf16 gather + pipelined bf16 MFMA GEMM.
// Round-16 (latency attack on the gather — R5 showed it is latency-bound,
// not VALU-bound: ~24% per-SIMD issue, depth-5 dependent load chain):
//   - permRec int4{start,cnt,seg} written at the PERMUTED slot in segOff:
//     gather does 1 coalesced load instead of perm->off->off+1 (off[] deleted)
//   - permMax[chunk] (max degree per 16-seg chunk, LDS atomicMax in segOff):
//     replaces the 4x shfl_xor wave reduce -> one independent load
//   - 2 chunks per wave (32 segs): two independent dependency streams,
//     8 outstanding x-loads; waves halve, MLP/wave doubles
//   - v_cvt_pk_bf16_f32 epilogue (same RNE rounding, ~1/3 the pack instr)
//
//   seg(e) = rel(e)*nN + src(e)          (numSeg = nRel*nN)
//   agg[seg,:] = bf16( mean_{e in seg} x[dst_e,:] )
//   out = sum_r agg_r @ W_r^T + x @ root^T + bias   (MFMA 16x16x32 bf16)

#define D 128
#define SCAN_CHUNK 2048
#define SEG_BITS 9
#define SEGS_PER_BUCKET 512
#define NBLK 128            // blocks for histA/scatterA
#define NDEG 32             // degree buckets

typedef __attribute__((ext_vector_type(8))) short short8;
typedef __attribute__((ext_vector_type(4))) float v4f;
typedef __attribute__((ext_vector_type(2))) float f32x2;
typedef __attribute__((ext_vector_type(4))) unsigned uint4v;

#define GLOAD_LDS16(gptr, lptr) \
    __builtin_amdgcn_global_load_lds((const __attribute__((address_space(1))) void*)(gptr), \
                                     (__attribute__((address_space(3))) void*)(lptr), 16, 0, 0)

__device__ __forceinline__ unsigned short f2b(float f) {
    union { float f; unsigned u; } v; v.f = f;
    unsigned r = v.u + 0x7fffu + ((v.u >> 16) & 1u);   // RNE
    return (unsigned short)(r >> 16);
}
__device__ __forceinline__ float blo(unsigned u) {
    union { unsigned u; float f; } v; v.u = u << 16; return v.f;
}
__device__ __forceinline__ float bhi(unsigned u) {
    union { unsigned u; float f; } v; v.u = u & 0xffff0000u; return v.f;
}

// ---------- fp32 -> bf16 bulk convert ----------
// x is written twice: slab-major xB[slice][node][32] (gather, L2-resident slices)
// and row-major xRow[node][128] (9th A slab for the GEMM).
__global__ void cvt_bf16_all(const float* __restrict__ x, long long nx,
                             const float* __restrict__ w, long long nw,
                             const float* __restrict__ root, long long nr,
                             unsigned short* __restrict__ xB,
                             unsigned short* __restrict__ xRow,
                             unsigned short* __restrict__ wB, int nN) {
    long long i = ((long long)blockIdx.x * blockDim.x + threadIdx.x) * 4;
    if (i < nx) {
        float4 v = *(const float4*)(x + i);
        uint2 p;
        p.x = (unsigned)f2b(v.x) | ((unsigned)f2b(v.y) << 16);
        p.y = (unsigned)f2b(v.z) | ((unsigned)f2b(v.w) << 16);
        long long n = i >> 7;
        int d = (int)(i & 127);
        size_t o = (size_t)(d >> 5) * (size_t)nN * 32 + (size_t)n * 32 + (d & 31);
        *(uint2*)(xB + o) = p;
        *(uint2*)(xRow + i) = p;
        return;
    }
    const float* src;
    unsigned short* dst;
    long long j;
    if (i < nx + nw) { src = w; dst = wB; j = i - nx; }
    else if (i < nx + nw + nr) { src = root; dst = wB + nw; j = i - nx - nw; }
    else return;
    float4 v = *(const float4*)(src + j);
    uint2 p;
    p.x = (unsigned)f2b(v.x) | ((unsigned)f2b(v.y) << 16);
    p.y = (unsigned)f2b(v.z) | ((unsigned)f2b(v.w) << 16);
    *(uint2*)(dst + j) = p;
}

// ---------- phase A: per-block bucket histogram (LDS atomics only) ----------
__global__ __launch_bounds__(256)
void histA(const int* __restrict__ ei, const int* __restrict__ et,
           int* __restrict__ blockHist, int nE, int nN, int B, int epb) {
    __shared__ int lh[1024];
    const int tid = threadIdx.x;
    for (int b = tid; b < B; b += 256) lh[b] = 0;
    __syncthreads();
    const int base = blockIdx.x * epb;
    const int lim = min(base + epb, nE);
    for (int e = base + tid; e < lim; e += 256) {
        int seg = et[e] * nN + ei[e];
        atomicAdd(&lh[seg >> SEG_BITS], 1);
    }
    __syncthreads();
    for (int b = tid; b < B; b += 256)
        blockHist[b * NBLK + blockIdx.x] = lh[b];
}

// ---------- scan of blockHist (bucket-major), 2 kernels + inline fixup ----------
__global__ __launch_bounds__(256)
void scan1(const int* __restrict__ in, int* __restrict__ excl,
           int* __restrict__ blockSums, int n) {
    __shared__ int t[256];
    const int tid = threadIdx.x;
    const int base = blockIdx.x * SCAN_CHUNK + tid * 8;
    int v[8];
    int tot = 0;
#pragma unroll
    for (int i = 0; i < 8; i++) {
        v[i] = (base + i < n) ? in[base + i] : 0;
        tot += v[i];
    }
    t[tid] = tot;
    __syncthreads();
    for (int off = 1; off < 256; off <<= 1) {
        int add = (tid >= off) ? t[tid - off] : 0;
        __syncthreads();
        t[tid] += add;
        __syncthreads();
    }
    int run = t[tid] - tot;
#pragma unroll
    for (int i = 0; i < 8; i++) {
        if (base + i < n) excl[base + i] = run;
        run += v[i];
    }
    if (tid == 255) blockSums[blockIdx.x] = t[255];
}

__global__ __launch_bounds__(256)
void scan2(int* __restrict__ blockSums, int nb) {
    __shared__ int t[256];
    const int tid = threadIdx.x;
    int v = (tid < nb) ? blockSums[tid] : 0;
    t[tid] = v;
    __syncthreads();
    for (int off = 1; off < 256; off <<= 1) {
        int add = (tid >= off) ? t[tid - off] : 0;
        __syncthreads();
        t[tid] += add;
        __syncthreads();
    }
    if (tid < nb) blockSums[tid] = t[tid] - v;
}

// ---------- phase C: bucket scatter (adds blockSums fix-up inline) ----------
__global__ __launch_bounds__(256)
void scatterA(const int* __restrict__ ei, const int* __restrict__ et,
              const int* __restrict__ scanned, const int* __restrict__ blockSums,
              unsigned* __restrict__ bucketEdges,
              int nE, int nN, int B, int epb) {
    __shared__ int cur[1024];
    const int tid = threadIdx.x;
    for (int b = tid; b < B; b += 256) {
        int idx = b * NBLK + blockIdx.x;
        cur[b] = scanned[idx] + blockSums[idx >> 11];   // SCAN_CHUNK = 2048
    }
    __syncthreads();
    const int base = blockIdx.x * epb;
    const int lim = min(base + epb, nE);
    for (int e = base + tid; e < lim; e += 256) {
        int seg = et[e] * nN + ei[e];
        int bkt = seg >> SEG_BITS;
        unsigned pk = ((unsigned)(seg & (SEGS_PER_BUCKET - 1)) << 16) | (unsigned)ei[nE + e];
        int pos = atomicAdd(&cur[bkt], 1);
        bucketEdges[pos] = pk;
    }
}

// ---------- phase D: seg offsets + sorted ushort dst + permRec/permMax ----------
// Block-local degree binning (64-seg sub-windows). Writes, at the PERMUTED
// slot, permRec = {start, cnt, seg, 0} (one gather load replaces
// perm->off->off+1), and permMax[chunk] = max degree of each 16-seg chunk
// (replaces the gather's shfl_xor max-reduce).
__global__ __launch_bounds__(256)
void segOff(const unsigned* __restrict__ bucketEdges, const int* __restrict__ scanned,
            const int* __restrict__ blockSums,
            int4* __restrict__ permRec, unsigned short* __restrict__ sortedDst,
            int* __restrict__ permMax, int nE, int numSeg, int B) {
    __shared__ int lh[SEGS_PER_BUCKET];
    __shared__ int sc[256];
    __shared__ int lcur[SEGS_PER_BUCKET];
    __shared__ int dcnt[256];    // [sub 0..7][deg 0..31]
    __shared__ int dbase[256];
    __shared__ int smax[32];     // [sub 0..7][chunk 0..3] max degree
    const int tid = threadIdx.x;
    const int b = blockIdx.x;
    const int i0 = b * NBLK;
    const int eBase = scanned[i0] + blockSums[i0 >> 11];
    int eEnd = nE;
    if (b + 1 < B) {
        const int i1 = (b + 1) * NBLK;
        eEnd = scanned[i1] + blockSums[i1 >> 11];
    }
    const int segBase = b * SEGS_PER_BUCKET;
    const int segLim = min(SEGS_PER_BUCKET, numSeg - segBase);

    lh[2 * tid] = 0; lh[2 * tid + 1] = 0;
    dcnt[tid] = 0;
    if (tid < 32) smax[tid] = 0;
    __syncthreads();
    for (int i = eBase + tid; i < eEnd; i += 256)
        atomicAdd(&lh[bucketEdges[i] >> 16], 1);
    __syncthreads();
    const int li0 = 2 * tid, li1 = 2 * tid + 1;
    const int sub = li0 >> 6;            // 64-seg sub-window (== li1>>6)
    int a0 = lh[li0], a1 = lh[li1];
    int b0 = min(a0, NDEG - 1), b1 = min(a1, NDEG - 1), r0 = 0, r1 = 0;
    if (li0 < segLim) r0 = atomicAdd(&dcnt[sub * NDEG + b0], 1);
    if (li1 < segLim) r1 = atomicAdd(&dcnt[sub * NDEG + b1], 1);
    sc[tid] = a0 + a1;
    __syncthreads();
    for (int o = 1; o < 256; o <<= 1) {
        int add = (tid >= o) ? sc[tid - o] : 0;
        __syncthreads();
        sc[tid] += add;
        __syncthreads();
    }
    int pairBase = sc[tid] - (a0 + a1);
    int g0 = eBase + pairBase;
    int g1 = g0 + a0;
    lcur[li0] = g0;
    lcur[li1] = g1;
    if (tid < 8) {               // per-sub serial 32-prefix for bucket bases
        int run = 0;
#pragma unroll
        for (int k = 0; k < NDEG; k++) { dbase[tid * NDEG + k] = run; run += dcnt[tid * NDEG + k]; }
    }
    __syncthreads();
    if (li0 < segLim) {
        int rk = dbase[sub * NDEG + b0] + r0;           // rank within 64-window
        permRec[segBase + sub * 64 + rk] = make_int4(g0, a0, segBase + li0, 0);
        atomicMax(&smax[(sub << 2) + (rk >> 4)], a0);
    }
    if (li1 < segLim) {
        int rk = dbase[sub * NDEG + b1] + r1;
        permRec[segBase + sub * 64 + rk] = make_int4(g1, a1, segBase + li1, 0);
        atomicMax(&smax[(sub << 2) + (rk >> 4)], a1);
    }
    for (int i = eBase + tid; i < eEnd; i += 256) {
        unsigned u = bucketEdges[i];
        int pos = atomicAdd(&lcur[u >> 16], 1);
        sortedDst[pos] = (unsigned short)(u & 0xFFFFu);
    }
    __syncthreads();
    if (tid < 32) permMax[b * 32 + tid] = smax[tid];
}

// ---------- gather: 2 chunks/wave, dim-sliced, 4 lanes/edge ----------
// blockIdx.y = slice (32 dims); per-slice xB slab = 3.2 MB -> per-XCD-L2
// resident. Each wave runs TWO independent 16-seg streams (8 outstanding
// x-loads) to hide the load-chain latency that limited R5.
__global__ __launch_bounds__(256)
void rgcn_gather(const unsigned short* __restrict__ xB,
                 const unsigned short* __restrict__ sortedDst,
                 const int4* __restrict__ permRec,
                 const int* __restrict__ permMax,
                 unsigned short* __restrict__ Abuf, int nN, int numSeg,
                 size_t SL, unsigned long long M) {
    const int tid = threadIdx.x;
    const int lane = tid & 63;
    const int idx4 = lane & 3;       // lane within 4-lane group (8 dims each)
    const int grp = lane >> 2;       // 16 groups per wave
    const int wv = tid >> 6;
    const int gsi0 = blockIdx.x * 128 + wv * 32 + grp;   // chunk 0 of this wave
    const int gsi1 = gsi0 + 16;                          // chunk 1
    const int sl = blockIdx.y;       // dims [sl*32, sl*32+32)
    const bool v0 = (gsi0 < numSeg);
    const bool v1 = (gsi1 < numSeg);

    int4 rc0 = v0 ? permRec[gsi0] : make_int4(0, 0, 0, 0);
    int4 rc1 = v1 ? permRec[gsi1] : make_int4(0, 0, 0, 0);
    int mx0 = v0 ? permMax[gsi0 >> 4] : 0;
    int mx1 = v1 ? permMax[gsi1 >> 4] : 0;
    mx0 = __builtin_amdgcn_readfirstlane(mx0);   // chunk-uniform -> scalar branch
    mx1 = __builtin_amdgcn_readfirstlane(mx1);

    const int start0 = rc0.x, cnt0 = v0 ? rc0.y : 0, seg0 = rc0.z;
    const int start1 = rc1.x, cnt1 = v1 ? rc1.y : 0, seg1 = rc1.z;

    f32x2 a0[4], a1[4];
#pragma unroll
    for (int i = 0; i < 4; i++) { a0[i] = (f32x2){0.f, 0.f}; a1[i] = (f32x2){0.f, 0.f}; }

    // slab-major: xB[sl][node][32]; each lane owns 8 consecutive dims
    const unsigned short* xSlab = xB + (size_t)sl * nN * 32 + idx4 * 8;

    const int mxm = max(mx0, mx1);
    for (int b = 0; b < mxm; b += 4) {
        uint4v w0[4], w1[4];
        int myD0 = 0, myD1 = 0;
        if (b < mx0) myD0 = (b + idx4 < cnt0) ? (int)sortedDst[start0 + b + idx4] : 0;
        if (b < mx1) myD1 = (b + idx4 < cnt1) ? (int)sortedDst[start1 + b + idx4] : 0;
        if (b < mx0) {
#pragma unroll
            for (int j = 0; j < 4; j++) {
                int dst = __shfl(myD0, grp * 4 + j);
                bool act = (b + j < cnt0);
                w0[j] = act ? *(const uint4v*)(xSlab + ((size_t)dst << 5))
                            : (uint4v){0u, 0u, 0u, 0u};
            }
        }
        if (b < mx1) {
#pragma unroll
            for (int j = 0; j < 4; j++) {
                int dst = __shfl(myD1, grp * 4 + j);
                bool act = (b + j < cnt1);
                w1[j] = act ? *(const uint4v*)(xSlab + ((size_t)dst << 5))
                            : (uint4v){0u, 0u, 0u, 0u};
            }
        }
        if (b < mx0) {
#pragma unroll
            for (int j = 0; j < 4; j++) {
                f32x2 t0 = (f32x2){blo(w0[j].x), bhi(w0[j].x)};
                f32x2 t1 = (f32x2){blo(w0[j].y), bhi(w0[j].y)};
                f32x2 t2 = (f32x2){blo(w0[j].z), bhi(w0[j].z)};
                f32x2 t3 = (f32x2){blo(w0[j].w), bhi(w0[j].w)};
                asm("v_pk_add_f32 %0, %0, %1" : "+v"(a0[0]) : "v"(t0));
                asm("v_pk_add_f32 %0, %0, %1" : "+v"(a0[1]) : "v"(t1));
                asm("v_pk_add_f32 %0, %0, %1" : "+v"(a0[2]) : "v"(t2));
                asm("v_pk_add_f32 %0, %0, %1" : "+v"(a0[3]) : "v"(t3));
            }
        }
        if (b < mx1) {
#pragma unroll
            for (int j = 0; j < 4; j++) {
                f32x2 t0 = (f32x2){blo(w1[j].x), bhi(w1[j].x)};
                f32x2 t1 = (f32x2){blo(w1[j].y), bhi(w1[j].y)};
                f32x2 t2 = (f32x2){blo(w1[j].z), bhi(w1[j].z)};
                f32x2 t3 = (f32x2){blo(w1[j].w), bhi(w1[j].w)};
                asm("v_pk_add_f32 %0, %0, %1" : "+v"(a1[0]) : "v"(t0));
                asm("v_pk_add_f32 %0, %0, %1" : "+v"(a1[1]) : "v"(t1));
                asm("v_pk_add_f32 %0, %0, %1" : "+v"(a1[2]) : "v"(t2));
                asm("v_pk_add_f32 %0, %0, %1" : "+v"(a1[3]) : "v"(t3));
            }
        }
    }

    if (v0) {
        float s = cnt0 > 0 ? 1.0f / (float)cnt0 : 0.f;
        const int r = (int)(((unsigned long long)seg0 * M) >> 48);  // seg / nN
        const int n = seg0 - r * nN;
        unsigned p0, p1, p2, p3;
        float e0, e1;
        e0 = a0[0].x * s; e1 = a0[0].y * s;
        asm("v_cvt_pk_bf16_f32 %0, %1, %2" : "=v"(p0) : "v"(e0), "v"(e1));
        e0 = a0[1].x * s; e1 = a0[1].y * s;
        asm("v_cvt_pk_bf16_f32 %0, %1, %2" : "=v"(p1) : "v"(e0), "v"(e1));
        e0 = a0[2].x * s; e1 = a0[2].y * s;
        asm("v_cvt_pk_bf16_f32 %0, %1, %2" : "=v"(p2) : "v"(e0), "v"(e1));
        e0 = a0[3].x * s; e1 = a0[3].y * s;
        asm("v_cvt_pk_bf16_f32 %0, %1, %2" : "=v"(p3) : "v"(e0), "v"(e1));
        uint4v pkt = (uint4v){p0, p1, p2, p3};
        __builtin_nontemporal_store(pkt,
            (uint4v*)(Abuf + (size_t)r * SL + (size_t)n * D + sl * 32 + idx4 * 8));
    }
    if (v1) {
        float s = cnt1 > 0 ? 1.0f / (float)cnt1 : 0.f;
        const int r = (int)(((unsigned long long)seg1 * M) >> 48);
        const int n = seg1 - r * nN;
        unsigned p0, p1, p2, p3;
        float e0, e1;
        e0 = a1[0].x * s; e1 = a1[0].y * s;
        asm("v_cvt_pk_bf16_f32 %0, %1, %2" : "=v"(p0) : "v"(e0), "v"(e1));
        e0 = a1[1].x * s; e1 = a1[1].y * s;
        asm("v_cvt_pk_bf16_f32 %0, %1, %2" : "=v"(p1) : "v"(e0), "v"(e1));
        e0 = a1[2].x * s; e1 = a1[2].y * s;
        asm("v_cvt_pk_bf16_f32 %0, %1, %2" : "=v"(p2) : "v"(e0), "v"(e1));
        e0 = a1[3].x * s; e1 = a1[3].y * s;
        asm("v_cvt_pk_bf16_f32 %0, %1, %2" : "=v"(p3) : "v"(e0), "v"(e1));
        uint4v pkt = (uint4v){p0, p1, p2, p3};
        __builtin_nontemporal_store(pkt,
            (uint4v*)(Abuf + (size_t)r * SL + (size_t)n * D + sl * 32 + idx4 * 8));
    }
}

// ---------- MFMA GEMM: M=nN, N=128, K=(nRel+1)*128 ----------
// A = [nRel+1][nNalloc][128] contiguous (8 agg slabs + xRow); B = wB [nRel+1][128][128].
// Pipelined 2-phase: global_load_lds(16B) into linear LDS, st_8x16 XOR swizzle
// applied on the global SOURCE address; ds_read applies the same XOR. 1 barrier/step.
__global__ __launch_bounds__(256)
void rgcn_gemm_mfma(const unsigned short* __restrict__ A,
                    const unsigned short* __restrict__ wB,
                    const float* __restrict__ bias,
                    float* __restrict__ out, int nN, int nRel, size_t SL) {
    __shared__ __align__(16) unsigned short As[2][64 * 64];    // [buf][row][64k]
    __shared__ __align__(16) unsigned short Bs[2][128 * 64];   // [buf][ocol][64k]
    const int tid = threadIdx.x;
    const int wave = tid >> 6;
    const int lane = tid & 63;
    const int wm = wave & 1;
    const int wn = wave >> 1;
    const int m16 = lane & 15;
    const int q = lane >> 4;
    const int row0 = blockIdx.x * 64;

    v4f acc[2][4];
#pragma unroll
    for (int i = 0; i < 2; i++)
#pragma unroll
        for (int j = 0; j < 4; j++) acc[i][j] = (v4f){0.f, 0.f, 0.f, 0.f};

    // ds_read offsets (ushort idx), swizzle: granule g read at slot g ^ (row&7);
    // row&7 == m16&7 for all frags (row/ocol = mult-of-8 + m16).
    const int sw = m16 & 7;
    int aoff[2][2], boff[4][2];
#pragma unroll
    for (int mt = 0; mt < 2; mt++) {
        int row = wm * 32 + mt * 16 + m16;
#pragma unroll
        for (int kb = 0; kb < 2; kb++)
            aoff[mt][kb] = row * 64 + (((kb * 4 + q) ^ sw) * 8);
    }
#pragma unroll
    for (int nt = 0; nt < 4; nt++) {
        int o = wn * 64 + nt * 16 + m16;
#pragma unroll
        for (int kb = 0; kb < 2; kb++)
            boff[nt][kb] = o * 64 + (((kb * 4 + q) ^ sw) * 8);
    }

    // staging: lane l of issue i writes LDS slot (base_i + l); slot -> row=slot>>3,
    // gs=slot&7; source granule gd = gs ^ (row&7) = (l&7) ^ (l>>3) (i adds 8 rows).
    const int l8 = lane >> 3;
    const int gd = (lane & 7) ^ l8;
    const size_t aBase = (size_t)(row0 + wave * 16 + l8) * D + gd * 8;  // elements
    const size_t bBase = (size_t)(wave * 32 + l8) * D + gd * 8;

    const int nT = 2 * (nRel + 1);    // 18 K-steps of 64

#define STAGE(buf, t) do { \
        const int s_ = (t) >> 1, h_ = (t) & 1; \
        const unsigned short* ga_ = A + (size_t)s_ * SL + h_ * 64 + aBase; \
        const unsigned short* gb_ = wB + (size_t)s_ * (D * D) + h_ * 64 + bBase; \
        GLOAD_LDS16(ga_,        &As[buf][(wave * 2 + 0) * 512]); \
        GLOAD_LDS16(ga_ + 1024, &As[buf][(wave * 2 + 1) * 512]); \
        GLOAD_LDS16(gb_,        &Bs[buf][(wave * 4 + 0) * 512]); \
        GLOAD_LDS16(gb_ + 1024, &Bs[buf][(wave * 4 + 1) * 512]); \
        GLOAD_LDS16(gb_ + 2048, &Bs[buf][(wave * 4 + 2) * 512]); \
        GLOAD_LDS16(gb_ + 3072, &Bs[buf][(wave * 4 + 3) * 512]); \
    } while (0)

    STAGE(0, 0);
    __syncthreads();                    // vmcnt(0) drain emitted by compiler
    int cur = 0;
    for (int t = 0; t < nT; ++t) {
        if (t + 1 < nT) STAGE(cur ^ 1, t + 1);   // next tile in flight over compute
        const unsigned short* Ab = As[cur];
        const unsigned short* Bb = Bs[cur];
        short8 a[2][2], b[4][2];
#pragma unroll
        for (int kb = 0; kb < 2; kb++) {
#pragma unroll
            for (int mt = 0; mt < 2; mt++)
                a[mt][kb] = *(const short8*)&Ab[aoff[mt][kb]];
#pragma unroll
            for (int nt = 0; nt < 4; nt++)
                b[nt][kb] = *(const short8*)&Bb[boff[nt][kb]];
        }
#pragma unroll
        for (int kb = 0; kb < 2; kb++)
#pragma unroll
            for (int mt = 0; mt < 2; mt++)
#pragma unroll
                for (int nt = 0; nt < 4; nt++)
                    acc[mt][nt] = __builtin_amdgcn_mfma_f32_16x16x32_bf16(
                        a[mt][kb], b[nt][kb], acc[mt][nt], 0, 0, 0);
        __syncthreads();
        cur ^= 1;
    }
#undef STAGE

#pragma unroll
    for (int mt = 0; mt < 2; mt++) {
#pragma unroll
        for (int nt = 0; nt < 4; nt++) {
            int col = wn * 64 + nt * 16 + m16;
            float bi = bias[col];
#pragma unroll
            for (int reg = 0; reg < 4; reg++) {
                int rrow = row0 + wm * 32 + mt * 16 + q * 4 + reg;
                if (rrow < nN)
                    out[(size_t)rrow * D + col] = acc[mt][nt][reg] + bi;
            }
        }
    }
}

extern "C" void kernel_launch(void* const* d_in, const int* in_sizes, int n_in,
                              void* d_out, int out_size, void* d_ws, size_t ws_size,
                              hipStream_t stream) {
    const float* x    = (const float*)d_in[0];
    const int*   ei   = (const int*)d_in[1];
    const int*   et   = (const int*)d_in[2];
    const float* w    = (const float*)d_in[3];
    const float* root = (const float*)d_in[4];
    const float* bias = (const float*)d_in[5];
    float* out = (float*)d_out;

    const int nN   = in_sizes[0] / D;        // 50000 (< 65536 for ushort dst)
    const int nE   = in_sizes[2];
    const int nRel = in_sizes[3] / (D * D);
    const int numSeg = nRel * nN;
    const int B = (numSeg + SEGS_PER_BUCKET - 1) >> SEG_BITS;   // 782 (<= 1024)
    const int nBH = B * NBLK;
    const int epb = (nE + NBLK - 1) / NBLK;
    const int nNalloc = (nN + 63) & ~63;     // pad rows to 64; garbage rows benign
    const size_t SL = (size_t)nNalloc * D;   // elements per A slab
    const unsigned long long M = ((1ULL << 48) + nN - 1) / nN;  // magic for /nN

    // workspace layout (~162 MB; ws proven >= 218 MB in round 4)
    char* p = (char*)d_ws;
    unsigned* bucketEdges   = (unsigned*)p;        p += (size_t)nE * sizeof(unsigned);
    unsigned short* sortedDst = (unsigned short*)p; p += (size_t)nE * sizeof(unsigned short);
    p = (char*)(((uintptr_t)p + 255) & ~(uintptr_t)255);
    int* blockHist = (int*)p;  p += (size_t)nBH * sizeof(int);
    int* scanned   = (int*)p;  p += (size_t)nBH * sizeof(int);
    int* blockSums = (int*)p;  p += 256 * sizeof(int);
    p = (char*)(((uintptr_t)p + 255) & ~(uintptr_t)255);
    int4* permRec  = (int4*)p; p += (size_t)numSeg * sizeof(int4);
    int* permMax   = (int*)p;  p += (size_t)B * 32 * sizeof(int);
    p = (char*)(((uintptr_t)p + 255) & ~(uintptr_t)255);
    unsigned short* xB   = (unsigned short*)p;  p += (size_t)nN * D * sizeof(unsigned short);
    unsigned short* wBc  = (unsigned short*)p;  p += (size_t)(nRel + 1) * D * D * sizeof(unsigned short);
    p = (char*)(((uintptr_t)p + 255) & ~(uintptr_t)255);
    unsigned short* Abuf = (unsigned short*)p;     // [nRel+1][nNalloc][128]
    unsigned short* xRow = Abuf + (size_t)nRel * SL;

    const int nScanBlocks = (nBH + SCAN_CHUNK - 1) / SCAN_CHUNK;  // 49 <= 256

    histA<<<NBLK, 256, 0, stream>>>(ei, et, blockHist, nE, nN, B, epb);
    scan1<<<nScanBlocks, 256, 0, stream>>>(blockHist, scanned, blockSums, nBH);
    scan2<<<1, 256, 0, stream>>>(blockSums, nScanBlocks);
    scatterA<<<NBLK, 256, 0, stream>>>(ei, et, scanned, blockSums, bucketEdges, nE, nN, B, epb);
    segOff<<<B, 256, 0, stream>>>(bucketEdges, scanned, blockSums, permRec, sortedDst, permMax,
                                  nE, numSeg, B);

    long long nx = (long long)nN * D;
    long long nw = (long long)nRel * D * D;
    long long nr = (long long)D * D;
    long long ncvt = (nx + nw + nr) / 4;
    cvt_bf16_all<<<(int)((ncvt + 255) / 256), 256, 0, stream>>>(x, nx, w, nw, root, nr,
                                                                xB, xRow, wBc, nN);

    dim3 gg((numSeg + 127) / 128, 4);
    rgcn_gather<<<gg, 256, 0, stream>>>(xB, sortedDst, permRec, permMax, Abuf, nN, numSeg, SL, M);

    rgcn_gemm_mfma<<<(nN + 63) / 64, 256, 0, stream>>>(Abuf, wBc, bias, out, nN, nRel, SL);
}